// Round 3
// baseline (861.655 us; speedup 1.0000x reference)
//
#include <hip/hip_runtime.h>

typedef unsigned short u16;
typedef unsigned int u32;
typedef short short8 __attribute__((ext_vector_type(8)));
typedef float f32x4 __attribute__((ext_vector_type(4)));

#define T_LEN 512
#define BATCH 128
#define DIM 128
#define HID 128
#define NCLS 19

#define L2E 1.4426950408889634f
#define TL2E 2.8853901617765067f

static __device__ __forceinline__ u16 f2bf(float f) {
  u32 u = __float_as_uint(f);
  u32 r = (u + 0x7FFFu + ((u >> 16) & 1u)) >> 16;
  return (u16)r;
}
static __device__ __forceinline__ float bf2f(u16 h) {
  return __uint_as_float(((u32)h) << 16);
}
static __device__ __forceinline__ float exp2_f(float x) { return exp2f(x); }
static __device__ __forceinline__ float rcp_f(float x) { return __builtin_amdgcn_rcpf(x); }

// ---------------- embedding gather + cast to bf16, layout xs[t*B+b][d] -------------
__global__ __launch_bounds__(256) void k_embed(const int* __restrict__ ids,
                                               const float* __restrict__ table,
                                               u16* __restrict__ xs) {
  int i = blockIdx.x * 256 + threadIdx.x;
  int e = i * 4;               // element index, total T*B*D = 8388608
  int m = e >> 7;              // row = t*B + b
  int col = e & 127;
  int t = m >> 7, b = m & 127;
  int id = ids[b * T_LEN + t];
  float4 v = *(const float4*)(table + (size_t)id * DIM + col);
  ushort4 o;
  o.x = f2bf(v.x); o.y = f2bf(v.y); o.z = f2bf(v.z); o.w = f2bf(v.w);
  *(ushort4*)(xs + (size_t)m * DIM + col) = o;
}

// ---------------- weight prep ------------------------------------------------------
// Gate-interleave permutation p = 4u+q <-> original col j = q*128+u.
// wt_bf[dir][p][k 0..255] = K_dir[k][j(p)] * scale(q), bf16.  (rows 0-127 = x, 128-255 = h)
// scale: q==1 (cand, tanh) -> 2*log2e, else log2e.  bias_pre[dir*512+p] = (b_j + (q==2)) * scale.
__global__ __launch_bounds__(256) void k_prep(const float* __restrict__ fw_k,
                                              const float* __restrict__ bw_k,
                                              const float* __restrict__ fw_b,
                                              const float* __restrict__ bw_b,
                                              u16* __restrict__ wt_bf,
                                              float* __restrict__ bias_pre) {
  int wg = blockIdx.x;
  int tid = threadIdx.x;
  if (wg < 1024) {
    int i = wg * 256 + tid;        // 0..262143
    int n = i >> 8, k = i & 255;   // n = dir*512 + p
    int dir = n >> 9, p = n & 511;
    int u = p >> 2, q = p & 3;
    int j = q * 128 + u;
    float sc = (q == 1) ? TL2E : L2E;
    const float* K = dir ? bw_k : fw_k;
    wt_bf[i] = f2bf(K[k * 512 + j] * sc);
  } else {
    for (int uu = 0; uu < 4; uu++) {
      int n = uu * 256 + tid;
      int dir = n >> 9, p = n & 511;
      int u = p >> 2, q = p & 3;
      int j = q * 128 + u;
      float sc = (q == 1) ? TL2E : L2E;
      float bv = (dir ? bw_b : fw_b)[j] + (q == 2 ? 1.0f : 0.0f);
      bias_pre[n] = bv * sc;
    }
  }
}

// ---------------- fused LSTM: MFMA recurrence, WG = (dir, 16 batches) ---------------
// z[p][cb] = sum_k W[k][j(p)] * [x;h][cb][k]  via mfma(A=W^T frags resident, B=x/h frags)
// C layout: col = lane&15 = batch cb, row = (lane>>4)*4 + reg = p -> reg q = gate of unit
// u = 16w + 4n + (lane>>4).  One activation chain per lane per n-tile, no shuffles.
__global__ __launch_bounds__(512, 2) void k_lstm(const u16* __restrict__ wt_bf,
                                                 const float* __restrict__ bias_pre,
                                                 const u16* __restrict__ xs,
                                                 u16* __restrict__ hs_fw,
                                                 u16* __restrict__ hs_bw) {
  __shared__ char hb[8192];   // double-buffered h[16 cb][128 u] bf16, XOR-swizzled
  int tid = threadIdx.x;
  int wg = blockIdx.x;
  int dir = wg >> 3, g = wg & 7;
  int w = tid >> 6, l = tid & 63;
  int cb = l & 15, g4 = l >> 4;

  // resident A-fragments: W^T (128 VGPRs)
  short8 wf[32];
#pragma unroll
  for (int n = 0; n < 4; n++) {
    const u16* wb = wt_bf + ((size_t)(dir * 512 + w * 64 + n * 16 + cb) * 256) + g4 * 8;
#pragma unroll
    for (int ks = 0; ks < 8; ks++)
      wf[n * 8 + ks] = *(const short8*)(wb + ks * 32);
  }
  f32x4 bias4[4];
#pragma unroll
  for (int n = 0; n < 4; n++)
    bias4[n] = *(const f32x4*)(bias_pre + dir * 512 + w * 64 + n * 16 + g4 * 4);
  float c[4] = {0.f, 0.f, 0.f, 0.f};

  int swz = (cb & 7) << 4;
  int roff[4], woff[4];
#pragma unroll
  for (int ks = 0; ks < 4; ks++)
    roff[ks] = (cb * 256 + ks * 64 + g4 * 16) ^ swz;
#pragma unroll
  for (int n = 0; n < 4; n++) {
    int u = w * 16 + n * 4 + g4;
    woff[n] = (cb * 256 + u * 2) ^ swz;
  }
  // zero buf0
  u32* hz = (u32*)hb;
  hz[tid] = 0; hz[tid + 512] = 0;
  __syncthreads();

  int t0a = dir ? (T_LEN - 1) : 0;
  int stp = dir ? -1 : 1;
  u16* hsout = dir ? hs_bw : hs_fw;
  long step2 = (long)stp * 32768;   // 2 time steps, in elements (16384/step)

  const u16* pxA = xs + ((size_t)(t0a * 128 + g * 16 + cb) * 128) + g4 * 8;
  const u16* pxB = pxA + (long)stp * 16384;
  u16* phA = hsout + ((size_t)(t0a * 128 + g * 16 + cb) * 128) + w * 16 + g4;
  u16* phB = phA + (long)stp * 16384;

  short8 xA[4], xB[4];
#pragma unroll
  for (int ks = 0; ks < 4; ks++) xA[ks] = *(const short8*)(pxA + ks * 32);
#pragma unroll
  for (int ks = 0; ks < 4; ks++) xB[ks] = *(const short8*)(pxB + ks * 32);
  pxA += step2; pxB += step2;

#define LSTM_STEP(XREG, CURO, NXTO, PX, PH, TGUARD)                                   \
  do {                                                                                \
    short8 xn0 = XREG[0], xn1 = XREG[1], xn2 = XREG[2], xn3 = XREG[3];                \
    if (TGUARD) {                                                                     \
      xn0 = *(const short8*)(PX);       xn1 = *(const short8*)(PX + 32);              \
      xn2 = *(const short8*)(PX + 64);  xn3 = *(const short8*)(PX + 96);              \
    }                                                                                 \
    PX += step2;                                                                      \
    short8 hf0 = *(const short8*)(hb + CURO + roff[0]);                               \
    short8 hf1 = *(const short8*)(hb + CURO + roff[1]);                               \
    short8 hf2 = *(const short8*)(hb + CURO + roff[2]);                               \
    short8 hf3 = *(const short8*)(hb + CURO + roff[3]);                               \
    float hval[4];                                                                    \
    _Pragma("unroll")                                                                 \
    for (int n = 0; n < 4; n++) {                                                     \
      f32x4 acc = bias4[n];                                                           \
      acc = __builtin_amdgcn_mfma_f32_16x16x32_bf16(wf[n*8+0], XREG[0], acc, 0,0,0);  \
      acc = __builtin_amdgcn_mfma_f32_16x16x32_bf16(wf[n*8+1], XREG[1], acc, 0,0,0);  \
      acc = __builtin_amdgcn_mfma_f32_16x16x32_bf16(wf[n*8+2], XREG[2], acc, 0,0,0);  \
      acc = __builtin_amdgcn_mfma_f32_16x16x32_bf16(wf[n*8+3], XREG[3], acc, 0,0,0);  \
      acc = __builtin_amdgcn_mfma_f32_16x16x32_bf16(wf[n*8+4], hf0, acc, 0,0,0);      \
      acc = __builtin_amdgcn_mfma_f32_16x16x32_bf16(wf[n*8+5], hf1, acc, 0,0,0);      \
      acc = __builtin_amdgcn_mfma_f32_16x16x32_bf16(wf[n*8+6], hf2, acc, 0,0,0);      \
      acc = __builtin_amdgcn_mfma_f32_16x16x32_bf16(wf[n*8+7], hf3, acc, 0,0,0);      \
      float A2 = exp2_f(-acc[0]);                /* 2^-Zi */                          \
      float B2 = exp2_f(acc[1]);                 /* e^{2zj} */                        \
      float F2 = exp2_f(-acc[2]);                /* 2^-Zf (bias incl. +1) */          \
      float O2 = exp2_f(-acc[3]);                /* 2^-Zo */                          \
      float r1 = rcp_f((1.f + A2) * (1.f + B2));                                      \
      float rf = rcp_f(1.f + F2);                                                     \
      float cn = fmaf(c[n], rf, (B2 - 1.f) * r1);                                     \
      c[n] = cn;                                                                      \
      float C2 = exp2_f(cn * TL2E);              /* e^{2c} */                         \
      float r2 = rcp_f((1.f + C2) * (1.f + O2));                                      \
      hval[n] = (C2 - 1.f) * r2;                 /* tanh(c)*sig(zo) */                \
    }                                                                                 \
    u32 pk01, pk23;                                                                   \
    asm("v_cvt_pk_bf16_f32 %0, %1, %2" : "=v"(pk01) : "v"(hval[0]), "v"(hval[1]));    \
    asm("v_cvt_pk_bf16_f32 %0, %1, %2" : "=v"(pk23) : "v"(hval[2]), "v"(hval[3]));    \
    u32 hi01 = pk01 >> 16, hi23 = pk23 >> 16;                                         \
    *(u16*)(hb + NXTO + woff[0]) = (u16)pk01;                                         \
    *(u16*)(hb + NXTO + woff[1]) = (u16)hi01;                                         \
    *(u16*)(hb + NXTO + woff[2]) = (u16)pk23;                                         \
    *(u16*)(hb + NXTO + woff[3]) = (u16)hi23;                                         \
    PH[0] = (u16)pk01; PH[4] = (u16)hi01; PH[8] = (u16)pk23; PH[12] = (u16)hi23;      \
    PH += step2;                                                                      \
    asm volatile("s_waitcnt lgkmcnt(0)" ::: "memory");                                \
    __builtin_amdgcn_s_barrier();                                                     \
    asm volatile("" ::: "memory");                                                    \
    XREG[0] = xn0; XREG[1] = xn1; XREG[2] = xn2; XREG[3] = xn3;                       \
  } while (0)

  for (int tt = 0; tt < 256; tt++) {
    int gok = (tt < 255);
    LSTM_STEP(xA, 0, 4096, pxA, phA, gok);
    LSTM_STEP(xB, 4096, 0, pxB, phB, gok);
  }
#undef LSTM_STEP
}

// ---------------- attention + FC + argmax, single pass over hs ----------------------
__global__ __launch_bounds__(512) void k_attn(const u16* __restrict__ hsf,
                                              const u16* __restrict__ hsb,
                                              const float* __restrict__ att_w,
                                              const float* __restrict__ fc_w,
                                              const float* __restrict__ fc_b,
                                              float* __restrict__ out) {
  __shared__ float rsum[8][128];
  __shared__ float esums[8];
  __shared__ float hstar[128];
  __shared__ float lg[NCLS];
  int tid = threadIdx.x, b = blockIdx.x;
  int w = tid >> 6, l = tid & 63;
  float2 aw = *(const float2*)(att_w + 2 * l);
  float r0 = 0.f, r1 = 0.f, es = 0.f;
  for (int t = w; t < T_LEN; t += 8) {
    size_t o = ((size_t)t * 128 + b) * 128 + 2 * l;
    u32 vf = *(const u32*)(hsf + o);
    u32 vb = *(const u32*)(hsb + o);
    float h0 = bf2f((u16)vf) + bf2f((u16)vb);
    float h1 = bf2f((u16)(vf >> 16)) + bf2f((u16)(vb >> 16));
    float e0 = exp2_f(h0 * TL2E);
    float th0 = (e0 - 1.f) * rcp_f(e0 + 1.f);
    float e1 = exp2_f(h1 * TL2E);
    float th1 = (e1 - 1.f) * rcp_f(e1 + 1.f);
    float s = fmaf(th0, aw.x, th1 * aw.y);
#pragma unroll
    for (int o2 = 32; o2 >= 1; o2 >>= 1) s += __shfl_xor(s, o2, 64);
    float e = exp2_f(s * L2E);     // no max-subtraction: |s| bounded, e^s safe in f32
    r0 = fmaf(e, h0, r0); r1 = fmaf(e, h1, r1); es += e;
  }
  rsum[w][2 * l] = r0;
  rsum[w][2 * l + 1] = r1;
  if (l == 0) esums[w] = es;
  __syncthreads();
  if (tid < 128) {
    float r = 0.f, et = 0.f;
#pragma unroll
    for (int i = 0; i < 8; i++) { r += rsum[i][tid]; et += esums[i]; }
    float rr = r / et;
    float e2 = exp2_f(rr * TL2E);
    hstar[tid] = (e2 - 1.f) * rcp_f(e2 + 1.f);
  }
  __syncthreads();
  if (tid < NCLS) {
    float acc = fc_b[tid];
#pragma unroll 4
    for (int hh = 0; hh < 128; hh++) acc = fmaf(hstar[hh], fc_w[hh * NCLS + tid], acc);
    out[b * NCLS + tid] = acc;
    lg[tid] = acc;
  }
  __syncthreads();
  if (tid == 0) {
    int best = 0; float bv = lg[0];
    for (int l2 = 1; l2 < NCLS; l2++)
      if (lg[l2] > bv) { bv = lg[l2]; best = l2; }
    out[2432 + b] = (float)best;   // predict_label_ids
    out[2561 + b] = (float)best;   // probabilities (argmax of softmax == argmax)
  }
}

// ---------------- l2 loss ----------------------------------------------------------
__global__ __launch_bounds__(256) void k_l2(const float* __restrict__ fc_w,
                                            const float* __restrict__ fc_b,
                                            float* __restrict__ out) {
  __shared__ float red[256];
  int tid = threadIdx.x;
  float a = 0.f;
  for (int i = tid; i < 128 * NCLS; i += 256) a += fc_w[i] * fc_w[i];
  if (tid < NCLS) a += fc_b[tid] * fc_b[tid];
  red[tid] = a; __syncthreads();
  for (int s = 128; s >= 1; s >>= 1) {
    if (tid < s) red[tid] += red[tid + s];
    __syncthreads();
  }
  if (tid == 0) out[2560] = 0.5f * red[0];
}

extern "C" void kernel_launch(void* const* d_in, const int* in_sizes, int n_in,
                              void* d_out, int out_size, void* d_ws, size_t ws_size,
                              hipStream_t stream) {
  const int* ids = (const int*)d_in[0];
  const float* table = (const float*)d_in[1];
  const float* fw_k = (const float*)d_in[2];
  const float* fw_b = (const float*)d_in[3];
  const float* bw_k = (const float*)d_in[4];
  const float* bw_b = (const float*)d_in[5];
  const float* att_w = (const float*)d_in[6];
  const float* fc_w = (const float*)d_in[7];
  const float* fc_b = (const float*)d_in[8];
  float* out = (float*)d_out;
  char* ws = (char*)d_ws;

  u16* xs = (u16*)(ws + 0);                    // 16,777,216 B   xs[t*128+b][128] bf16
  u16* wt_bf = (u16*)(ws + 16777216);          //    524,288 B   [2][512][256] bf16
  float* bias_pre = (float*)(ws + 17301504);   //      4,096 B
  u16* hs_fw = (u16*)(ws + 17305600);          // 16,777,216 B   [t][b][u] bf16
  u16* hs_bw = (u16*)(ws + 34082816);          // 16,777,216 B   (end 50,860,032)

  hipLaunchKernelGGL(k_embed, dim3(8192), dim3(256), 0, stream, ids, table, xs);
  hipLaunchKernelGGL(k_prep, dim3(1025), dim3(256), 0, stream, fw_k, bw_k, fw_b, bw_b,
                     wt_bf, bias_pre);
  hipLaunchKernelGGL(k_lstm, dim3(16), dim3(512), 0, stream, wt_bf, bias_pre, xs,
                     hs_fw, hs_bw);
  hipLaunchKernelGGL(k_attn, dim3(128), dim3(512), 0, stream, hs_fw, hs_bw, att_w,
                     fc_w, fc_b, out);
  hipLaunchKernelGGL(k_l2, dim3(1), dim3(256), 0, stream, fc_w, fc_b, out);
}

// Round 5
// 692.050 us; speedup vs baseline: 1.2451x; 1.2451x over previous
//
#include <hip/hip_runtime.h>

typedef unsigned short u16;
typedef unsigned int u32;
typedef short short8 __attribute__((ext_vector_type(8)));
typedef float f32x4 __attribute__((ext_vector_type(4)));

#define T_LEN 512
#define NCLS 19

#define L2E 1.4426950408889634f
#define TL2E 2.8853901617765067f

static __device__ __forceinline__ u16 f2bf(float f) {
  u32 u = __float_as_uint(f);
  u32 r = (u + 0x7FFFu + ((u >> 16) & 1u)) >> 16;
  return (u16)r;
}
static __device__ __forceinline__ float bf2f(u16 h) {
  return __uint_as_float(((u32)h) << 16);
}
static __device__ __forceinline__ float rcp_f(float x) { return __builtin_amdgcn_rcpf(x); }
// native v_exp_f32 via the COMPILER INTRINSIC (hazards modeled; not raw asm)
static __device__ __forceinline__ float ex2(float x) { return __builtin_amdgcn_exp2f(x); }

// ---------------- embedding gather + cast to bf16, layout xs[t*B+b][d] -------------
__global__ __launch_bounds__(256) void k_embed(const int* __restrict__ ids,
                                               const float* __restrict__ table,
                                               u16* __restrict__ xs) {
  int i = blockIdx.x * 256 + threadIdx.x;
  int e = i * 4;               // element index, total T*B*D = 8388608
  int m = e >> 7;              // row = t*B + b
  int col = e & 127;
  int t = m >> 7, b = m & 127;
  int id = ids[b * T_LEN + t];
  float4 v = *(const float4*)(table + (size_t)id * 128 + col);
  ushort4 o;
  o.x = f2bf(v.x); o.y = f2bf(v.y); o.z = f2bf(v.z); o.w = f2bf(v.w);
  *(ushort4*)(xs + (size_t)m * 128 + col) = o;
}

// ---------------- weight prep ------------------------------------------------------
// p-layout (per dir): p = w*64 + n*16 + g4*4 + q  <->  unit u = w*16 + g4*4 + n, gate q.
// Original kernel column j = q*128 + u.  Weights pre-scaled by log2e (2*log2e for q==1)
// so activations use native v_exp_f32.  wt_bf[dir][p][k 0..255] (k<128 = x rows, else h).
__global__ __launch_bounds__(256) void k_prep(const float* __restrict__ fw_k,
                                              const float* __restrict__ bw_k,
                                              const float* __restrict__ fw_b,
                                              const float* __restrict__ bw_b,
                                              u16* __restrict__ wt_bf,
                                              float* __restrict__ bias_pre) {
  int wg = blockIdx.x;
  int tid = threadIdx.x;
  if (wg < 1024) {
    int i = wg * 256 + tid;        // 0..262143
    int n = i >> 8, k = i & 255;   // n = dir*512 + p
    int dir = n >> 9, p = n & 511;
    int w = p >> 6, nt = (p >> 4) & 3, g4 = (p >> 2) & 3, q = p & 3;
    int u = w * 16 + g4 * 4 + nt;
    int j = q * 128 + u;
    float sc = (q == 1) ? TL2E : L2E;
    const float* K = dir ? bw_k : fw_k;
    wt_bf[i] = f2bf(K[k * 512 + j] * sc);
  } else {
    for (int uu = 0; uu < 4; uu++) {
      int n = uu * 256 + tid;
      int dir = n >> 9, p = n & 511;
      int w = p >> 6, nt = (p >> 4) & 3, g4 = (p >> 2) & 3, q = p & 3;
      int u = w * 16 + g4 * 4 + nt;
      int j = q * 128 + u;
      float sc = (q == 1) ? TL2E : L2E;
      float bv = (dir ? bw_b : fw_b)[j] + (q == 2 ? 1.0f : 0.0f);
      bias_pre[n] = bv * sc;
    }
  }
}

// ---------------- fused LSTM: MFMA recurrence, WG = (dir, 16 batches) ---------------
// Round-3-proven schedule (single fused 8-MFMA chain per n-tile, xn temp prefetch,
// lgkmcnt(0)+s_barrier per step).  Only deltas vs the passing kernel: contiguous-unit
// permutation -> ONE uint2 LDS write + ONE uint2 global store per lane per step.
__global__ __launch_bounds__(512, 2) void k_lstm(const u16* __restrict__ wt_bf,
                                                 const float* __restrict__ bias_pre,
                                                 const u16* __restrict__ xs,
                                                 u16* __restrict__ hs_fw,
                                                 u16* __restrict__ hs_bw) {
  __shared__ char hb[8192];   // double-buffered h[16 cb][128 u] bf16, XOR-swizzled
  int tid = threadIdx.x;
  int wg = blockIdx.x;
  int dir = wg >> 3, g = wg & 7;
  int w = tid >> 6, l = tid & 63;
  int cb = l & 15, g4 = l >> 4;

  // resident A-fragments: W^T (128 regs)
  short8 wf[32];
#pragma unroll
  for (int n = 0; n < 4; n++) {
    const u16* wb = wt_bf + ((size_t)(dir * 512 + w * 64 + n * 16 + cb) * 256) + g4 * 8;
#pragma unroll
    for (int ks = 0; ks < 8; ks++)
      wf[n * 8 + ks] = *(const short8*)(wb + ks * 32);
  }
  f32x4 bias4[4];
#pragma unroll
  for (int n = 0; n < 4; n++)
    bias4[n] = *(const f32x4*)(bias_pre + dir * 512 + w * 64 + n * 16 + g4 * 4);
  float c[4] = {0.f, 0.f, 0.f, 0.f};

  int swz = (cb & 7) << 4;
  int roff[4];
#pragma unroll
  for (int ks = 0; ks < 4; ks++)
    roff[ks] = (cb * 256 + ks * 64 + g4 * 16) ^ swz;
  int u0 = w * 16 + g4 * 4;
  int woff = (cb * 256 + u0 * 2) ^ swz;

  // zero buf0 (h(0) = 0)
  u32* hz = (u32*)hb;
  hz[tid] = 0; hz[tid + 512] = 0;
  __syncthreads();

  int t0a = dir ? (T_LEN - 1) : 0;
  int stp = dir ? -1 : 1;
  u16* hsout = dir ? hs_bw : hs_fw;
  long step1 = (long)stp * 16384;   // 1 time step, elements
  long step2 = 2 * step1;

  const u16* xbase = xs + ((size_t)(t0a * 128 + g * 16 + cb) * 128) + g4 * 8;
  u16* phA = hsout + ((size_t)(t0a * 128 + g * 16 + cb) * 128) + u0;
  u16* phB = phA + step1;

  short8 xA[4], xB[4];
#pragma unroll
  for (int ks = 0; ks < 4; ks++) xA[ks] = *(const short8*)(xbase + ks * 32);         // x(0)
  const u16* pxB0 = xbase + step1;
#pragma unroll
  for (int ks = 0; ks < 4; ks++) xB[ks] = *(const short8*)(pxB0 + ks * 32);          // x(1)
  const u16* pxA = xbase + step2;        // A-macro reloads x(t+2), t even
  const u16* pxB = pxB0 + step2;         // B-macro reloads x(t+2), t odd

#define HSTEP(XREG, CURO, NXTO, PXL, PH, GOK)                                           \
  do {                                                                                  \
    short8 xn0 = XREG[0], xn1 = XREG[1], xn2 = XREG[2], xn3 = XREG[3];                  \
    if (GOK) {                                                                          \
      xn0 = *(const short8*)(PXL);       xn1 = *(const short8*)(PXL + 32);              \
      xn2 = *(const short8*)(PXL + 64);  xn3 = *(const short8*)(PXL + 96);              \
    }                                                                                   \
    PXL += step2;                                                                       \
    short8 hf0 = *(const short8*)(hb + (CURO) + roff[0]);                               \
    short8 hf1 = *(const short8*)(hb + (CURO) + roff[1]);                               \
    short8 hf2 = *(const short8*)(hb + (CURO) + roff[2]);                               \
    short8 hf3 = *(const short8*)(hb + (CURO) + roff[3]);                               \
    float hval[4];                                                                      \
    _Pragma("unroll")                                                                   \
    for (int n = 0; n < 4; n++) {                                                       \
      f32x4 acc = bias4[n];                                                             \
      acc = __builtin_amdgcn_mfma_f32_16x16x32_bf16(wf[n * 8 + 0], XREG[0], acc, 0,0,0);\
      acc = __builtin_amdgcn_mfma_f32_16x16x32_bf16(wf[n * 8 + 1], XREG[1], acc, 0,0,0);\
      acc = __builtin_amdgcn_mfma_f32_16x16x32_bf16(wf[n * 8 + 2], XREG[2], acc, 0,0,0);\
      acc = __builtin_amdgcn_mfma_f32_16x16x32_bf16(wf[n * 8 + 3], XREG[3], acc, 0,0,0);\
      acc = __builtin_amdgcn_mfma_f32_16x16x32_bf16(wf[n * 8 + 4], hf0, acc, 0, 0, 0);  \
      acc = __builtin_amdgcn_mfma_f32_16x16x32_bf16(wf[n * 8 + 5], hf1, acc, 0, 0, 0);  \
      acc = __builtin_amdgcn_mfma_f32_16x16x32_bf16(wf[n * 8 + 6], hf2, acc, 0, 0, 0);  \
      acc = __builtin_amdgcn_mfma_f32_16x16x32_bf16(wf[n * 8 + 7], hf3, acc, 0, 0, 0);  \
      float A2 = ex2(-acc[0]);                 /* e^-zi           */                    \
      float B2 = ex2(acc[1]);                  /* e^{2zj}         */                    \
      float F2 = ex2(-acc[2]);                 /* e^-(zf+1)       */                    \
      float O2 = ex2(-acc[3]);                 /* e^-zo           */                    \
      float r1 = rcp_f((1.f + A2) * (1.f + B2));                                        \
      float rf = rcp_f(1.f + F2);                                                       \
      float cn = fmaf(c[n], rf, (B2 - 1.f) * r1);                                       \
      c[n] = cn;                                                                        \
      float C2 = ex2(cn * TL2E);               /* e^{2c}          */                    \
      float r2 = rcp_f((1.f + C2) * (1.f + O2));                                        \
      hval[n] = (C2 - 1.f) * r2;               /* tanh(c)*sig(zo) */                    \
    }                                                                                   \
    u32 pk01, pk23;                                                                     \
    asm("v_cvt_pk_bf16_f32 %0, %1, %2" : "=v"(pk01) : "v"(hval[0]), "v"(hval[1]));      \
    asm("v_cvt_pk_bf16_f32 %0, %1, %2" : "=v"(pk23) : "v"(hval[2]), "v"(hval[3]));      \
    *(uint2*)(hb + (NXTO) + woff) = make_uint2(pk01, pk23);                             \
    *(uint2*)(PH) = make_uint2(pk01, pk23);                                             \
    PH += step2;                                                                        \
    asm volatile("s_waitcnt lgkmcnt(0)" ::: "memory");                                  \
    __builtin_amdgcn_s_barrier();                                                       \
    asm volatile("" ::: "memory");                                                      \
    XREG[0] = xn0; XREG[1] = xn1; XREG[2] = xn2; XREG[3] = xn3;                         \
  } while (0)

  for (int tt = 0; tt < 256; tt++) {
    int gok = (tt < 255);
    HSTEP(xA, 0, 4096, pxA, phA, gok);      // step t = 2*tt
    HSTEP(xB, 4096, 0, pxB, phB, gok);      // step t = 2*tt+1
  }
#undef HSTEP
}

// ---------------- attention + FC + argmax, single pass over hs ----------------------
__global__ __launch_bounds__(512) void k_attn(const u16* __restrict__ hsf,
                                              const u16* __restrict__ hsb,
                                              const float* __restrict__ att_w,
                                              const float* __restrict__ fc_w,
                                              const float* __restrict__ fc_b,
                                              float* __restrict__ out) {
  __shared__ float rsum[8][128];
  __shared__ float esums[8];
  __shared__ float hstar[128];
  __shared__ float lg[NCLS];
  int tid = threadIdx.x, b = blockIdx.x;
  int w = tid >> 6, l = tid & 63;
  float2 aw = *(const float2*)(att_w + 2 * l);
  float r0 = 0.f, r1 = 0.f, es = 0.f;
  for (int t = w; t < T_LEN; t += 8) {
    size_t o = ((size_t)t * 128 + b) * 128 + 2 * l;
    u32 vf = *(const u32*)(hsf + o);
    u32 vb = *(const u32*)(hsb + o);
    float h0 = bf2f((u16)vf) + bf2f((u16)vb);
    float h1 = bf2f((u16)(vf >> 16)) + bf2f((u16)(vb >> 16));
    float e0 = ex2(h0 * TL2E);
    float th0 = (e0 - 1.f) * rcp_f(e0 + 1.f);
    float e1 = ex2(h1 * TL2E);
    float th1 = (e1 - 1.f) * rcp_f(e1 + 1.f);
    float s = fmaf(th0, aw.x, th1 * aw.y);
#pragma unroll
    for (int o2 = 32; o2 >= 1; o2 >>= 1) s += __shfl_xor(s, o2, 64);
    float e = ex2(s * L2E);      // no max-subtraction: |s| bounded, e^s safe in f32
    r0 = fmaf(e, h0, r0); r1 = fmaf(e, h1, r1); es += e;
  }
  rsum[w][2 * l] = r0;
  rsum[w][2 * l + 1] = r1;
  if (l == 0) esums[w] = es;
  __syncthreads();
  if (tid < 128) {
    float r = 0.f, et = 0.f;
#pragma unroll
    for (int i = 0; i < 8; i++) { r += rsum[i][tid]; et += esums[i]; }
    float rr = r / et;
    float e2 = ex2(rr * TL2E);
    hstar[tid] = (e2 - 1.f) * rcp_f(e2 + 1.f);
  }
  __syncthreads();
  if (tid < NCLS) {
    float acc = fc_b[tid];
#pragma unroll 4
    for (int hh = 0; hh < 128; hh++) acc = fmaf(hstar[hh], fc_w[hh * NCLS + tid], acc);
    out[b * NCLS + tid] = acc;
    lg[tid] = acc;
  }
  __syncthreads();
  if (tid == 0) {
    int best = 0; float bv = lg[0];
    for (int l2 = 1; l2 < NCLS; l2++)
      if (lg[l2] > bv) { bv = lg[l2]; best = l2; }
    out[2432 + b] = (float)best;   // predict_label_ids
    out[2561 + b] = (float)best;   // probabilities (argmax of softmax == argmax)
  }
}

// ---------------- l2 loss ----------------------------------------------------------
__global__ __launch_bounds__(256) void k_l2(const float* __restrict__ fc_w,
                                            const float* __restrict__ fc_b,
                                            float* __restrict__ out) {
  __shared__ float red[256];
  int tid = threadIdx.x;
  float a = 0.f;
  for (int i = tid; i < 128 * NCLS; i += 256) a += fc_w[i] * fc_w[i];
  if (tid < NCLS) a += fc_b[tid] * fc_b[tid];
  red[tid] = a; __syncthreads();
  for (int s = 128; s >= 1; s >>= 1) {
    if (tid < s) red[tid] += red[tid + s];
    __syncthreads();
  }
  if (tid == 0) out[2560] = 0.5f * red[0];
}

extern "C" void kernel_launch(void* const* d_in, const int* in_sizes, int n_in,
                              void* d_out, int out_size, void* d_ws, size_t ws_size,
                              hipStream_t stream) {
  const int* ids = (const int*)d_in[0];
  const float* table = (const float*)d_in[1];
  const float* fw_k = (const float*)d_in[2];
  const float* fw_b = (const float*)d_in[3];
  const float* bw_k = (const float*)d_in[4];
  const float* bw_b = (const float*)d_in[5];
  const float* att_w = (const float*)d_in[6];
  const float* fc_w = (const float*)d_in[7];
  const float* fc_b = (const float*)d_in[8];
  float* out = (float*)d_out;
  char* ws = (char*)d_ws;

  u16* xs = (u16*)(ws + 0);                    // 16,777,216 B   xs[t*128+b][128] bf16
  u16* wt_bf = (u16*)(ws + 16777216);          //    524,288 B   [2][512][256] bf16
  float* bias_pre = (float*)(ws + 17301504);   //      4,096 B
  u16* hs_fw = (u16*)(ws + 17305600);          // 16,777,216 B   [t][b][u] bf16
  u16* hs_bw = (u16*)(ws + 34082816);          // 16,777,216 B   (end 50,860,032)

  hipLaunchKernelGGL(k_embed, dim3(8192), dim3(256), 0, stream, ids, table, xs);
  hipLaunchKernelGGL(k_prep, dim3(1025), dim3(256), 0, stream, fw_k, bw_k, fw_b, bw_b,
                     wt_bf, bias_pre);
  hipLaunchKernelGGL(k_lstm, dim3(16), dim3(512), 0, stream, wt_bf, bias_pre, xs,
                     hs_fw, hs_bw);
  hipLaunchKernelGGL(k_attn, dim3(128), dim3(512), 0, stream, hs_fw, hs_bw, att_w,
                     fc_w, fc_b, out);
  hipLaunchKernelGGL(k_l2, dim3(1), dim3(256), 0, stream, fc_w, fc_b, out);
}

// Round 9
// 627.060 us; speedup vs baseline: 1.3741x; 1.1036x over previous
//
#include <hip/hip_runtime.h>

typedef unsigned short u16;
typedef unsigned int u32;
typedef short short8 __attribute__((ext_vector_type(8)));
typedef float f32x4 __attribute__((ext_vector_type(4)));

#define T_LEN 512
#define NCLS 19

#define L2E 1.4426950408889634f
#define TL2E 2.8853901617765067f

static __device__ __forceinline__ u16 f2bf(float f) {
  u32 u = __float_as_uint(f);
  u32 r = (u + 0x7FFFu + ((u >> 16) & 1u)) >> 16;
  return (u16)r;
}
static __device__ __forceinline__ float bf2f(u16 h) {
  return __uint_as_float(((u32)h) << 16);
}
static __device__ __forceinline__ float rcp_f(float x) { return __builtin_amdgcn_rcpf(x); }
// native v_exp_f32 via the COMPILER INTRINSIC (hazards modeled; not raw asm)
static __device__ __forceinline__ float ex2(float x) { return __builtin_amdgcn_exp2f(x); }

// ---------------- embedding gather + cast to bf16, layout xs[t*B+b][d] -------------
__global__ __launch_bounds__(256) void k_embed(const int* __restrict__ ids,
                                               const float* __restrict__ table,
                                               u16* __restrict__ xs) {
  int i = blockIdx.x * 256 + threadIdx.x;
  int e = i * 4;               // element index, total T*B*D = 8388608
  int m = e >> 7;              // row = t*B + b
  int col = e & 127;
  int t = m >> 7, b = m & 127;
  int id = ids[b * T_LEN + t];
  float4 v = *(const float4*)(table + (size_t)id * 128 + col);
  ushort4 o;
  o.x = f2bf(v.x); o.y = f2bf(v.y); o.z = f2bf(v.z); o.w = f2bf(v.w);
  *(ushort4*)(xs + (size_t)m * 128 + col) = o;
}

// ---------------- weight prep (r5-proven, UNCHANGED) -------------------------------
// p = w*64 + nt*16 + g4*4 + q  <->  unit u = w*16 + g4*4 + nt, gate q; col j = q*128+u.
// Weights pre-scaled by log2e (2*log2e for q==1); bias includes forget +1, scaled.
__global__ __launch_bounds__(256) void k_prep(const float* __restrict__ fw_k,
                                              const float* __restrict__ bw_k,
                                              const float* __restrict__ fw_b,
                                              const float* __restrict__ bw_b,
                                              u16* __restrict__ wt_bf,
                                              float* __restrict__ bias_pre) {
  int wg = blockIdx.x;
  int tid = threadIdx.x;
  if (wg < 1024) {
    int i = wg * 256 + tid;
    int n = i >> 8, k = i & 255;
    int dir = n >> 9, p = n & 511;
    int w = p >> 6, nt = (p >> 4) & 3, g4 = (p >> 2) & 3, q = p & 3;
    int u = w * 16 + g4 * 4 + nt;
    int j = q * 128 + u;
    float sc = (q == 1) ? TL2E : L2E;
    const float* K = dir ? bw_k : fw_k;
    wt_bf[i] = f2bf(K[k * 512 + j] * sc);
  } else {
    for (int uu = 0; uu < 4; uu++) {
      int n = uu * 256 + tid;
      int dir = n >> 9, p = n & 511;
      int w = p >> 6, nt = (p >> 4) & 3, g4 = (p >> 2) & 3, q = p & 3;
      int u = w * 16 + g4 * 4 + nt;
      int j = q * 128 + u;
      float sc = (q == 1) ? TL2E : L2E;
      float bv = (dir ? bw_b : fw_b)[j] + (q == 2 ? 1.0f : 0.0f);
      bias_pre[n] = bv * sc;
    }
  }
}

// ---------------- fused LSTM (r5-passing kernel; ONLY delta = direct-target x prefetch)
// z tile n: rows = gates p, cols = 16 batches.  Lane's 4 acc regs = gates i,j,f,o of
// unit u = w*16 + g4*4 + n; across n the 4 units are CONTIGUOUS -> single uint2 writes.
// Prefetch: x(t+2) is loaded DIRECTLY into XREG right after its last use (no temps,
// no copies) -> the compiler's vmcnt wait lands 2 steps later, not in the same step.
__global__ __launch_bounds__(512, 2) void k_lstm(const u16* __restrict__ wt_bf,
                                                 const float* __restrict__ bias_pre,
                                                 const u16* __restrict__ xs,
                                                 u16* __restrict__ hs_fw,
                                                 u16* __restrict__ hs_bw) {
  __shared__ char hb[8192];   // double-buffered h[16 cb][128 u] bf16, XOR-swizzled
  int tid = threadIdx.x;
  int wg = blockIdx.x;
  int dir = wg >> 3, g = wg & 7;
  int w = tid >> 6, l = tid & 63;
  int cb = l & 15, g4 = l >> 4;

  // resident A-frags: W^T (128 regs; compiler places in AGPRs, free for MFMA reads)
  short8 wf[32];
#pragma unroll
  for (int n = 0; n < 4; n++) {
    const u16* wb = wt_bf + ((size_t)(dir * 512 + w * 64 + n * 16 + cb) * 256) + g4 * 8;
#pragma unroll
    for (int ks = 0; ks < 8; ks++)
      wf[n * 8 + ks] = *(const short8*)(wb + ks * 32);
  }
  f32x4 bias4[4];
#pragma unroll
  for (int n = 0; n < 4; n++)
    bias4[n] = *(const f32x4*)(bias_pre + dir * 512 + w * 64 + n * 16 + g4 * 4);
  float c[4] = {0.f, 0.f, 0.f, 0.f};

  int swz = (cb & 7) << 4;
  int roff[4];
#pragma unroll
  for (int ks = 0; ks < 4; ks++)
    roff[ks] = (cb * 256 + ks * 64 + g4 * 16) ^ swz;
  int u0 = w * 16 + g4 * 4;
  int woff = (cb * 256 + u0 * 2) ^ swz;

  // zero buf0 (h(0) = 0)
  u32* hz = (u32*)hb;
  hz[tid] = 0; hz[tid + 512] = 0;
  __syncthreads();

  int t0a = dir ? (T_LEN - 1) : 0;
  int stp = dir ? -1 : 1;
  u16* hsout = dir ? hs_bw : hs_fw;
  long step1 = (long)stp * 16384;   // 1 time step, elements
  long step2 = 2 * step1;

  const u16* xbase = xs + ((size_t)(t0a * 128 + g * 16 + cb) * 128) + g4 * 8;
  u16* phA = hsout + ((size_t)(t0a * 128 + g * 16 + cb) * 128) + u0;
  u16* phB = phA + step1;

  short8 xA[4], xB[4];
#pragma unroll
  for (int ks = 0; ks < 4; ks++) xA[ks] = *(const short8*)(xbase + ks * 32);         // x(0)
  const u16* pxB0 = xbase + step1;
#pragma unroll
  for (int ks = 0; ks < 4; ks++) xB[ks] = *(const short8*)(pxB0 + ks * 32);          // x(1)
  const u16* pxA = xbase + step2;        // A-macro reloads x(t+2), t even
  const u16* pxB = pxB0 + step2;         // B-macro reloads x(t+2), t odd

#define HSTEP(XREG, CURO, NXTO, PXL, PH, GOK)                                           \
  do {                                                                                  \
    short8 hf0 = *(const short8*)(hb + (CURO) + roff[0]);                               \
    short8 hf1 = *(const short8*)(hb + (CURO) + roff[1]);                               \
    short8 hf2 = *(const short8*)(hb + (CURO) + roff[2]);                               \
    short8 hf3 = *(const short8*)(hb + (CURO) + roff[3]);                               \
    float hval[4];                                                                      \
    _Pragma("unroll")                                                                   \
    for (int n = 0; n < 4; n++) {                                                       \
      f32x4 acc = bias4[n];                                                             \
      acc = __builtin_amdgcn_mfma_f32_16x16x32_bf16(wf[n * 8 + 0], XREG[0], acc, 0,0,0);\
      acc = __builtin_amdgcn_mfma_f32_16x16x32_bf16(wf[n * 8 + 1], XREG[1], acc, 0,0,0);\
      acc = __builtin_amdgcn_mfma_f32_16x16x32_bf16(wf[n * 8 + 2], XREG[2], acc, 0,0,0);\
      acc = __builtin_amdgcn_mfma_f32_16x16x32_bf16(wf[n * 8 + 3], XREG[3], acc, 0,0,0);\
      acc = __builtin_amdgcn_mfma_f32_16x16x32_bf16(wf[n * 8 + 4], hf0, acc, 0, 0, 0);  \
      acc = __builtin_amdgcn_mfma_f32_16x16x32_bf16(wf[n * 8 + 5], hf1, acc, 0, 0, 0);  \
      acc = __builtin_amdgcn_mfma_f32_16x16x32_bf16(wf[n * 8 + 6], hf2, acc, 0, 0, 0);  \
      acc = __builtin_amdgcn_mfma_f32_16x16x32_bf16(wf[n * 8 + 7], hf3, acc, 0, 0, 0);  \
      float A2 = ex2(-acc[0]);                 /* e^-zi           */                    \
      float B2 = ex2(acc[1]);                  /* e^{2zj}         */                    \
      float F2 = ex2(-acc[2]);                 /* e^-(zf+1)       */                    \
      float O2 = ex2(-acc[3]);                 /* e^-zo           */                    \
      float r1 = rcp_f((1.f + A2) * (1.f + B2));                                        \
      float rf = rcp_f(1.f + F2);                                                       \
      float cn = fmaf(c[n], rf, (B2 - 1.f) * r1);                                       \
      c[n] = cn;                                                                        \
      float C2 = ex2(cn * TL2E);               /* e^{2c}          */                    \
      float r2 = rcp_f((1.f + C2) * (1.f + O2));                                        \
      hval[n] = (C2 - 1.f) * r2;               /* tanh(c)*sig(zo) */                    \
    }                                                                                   \
    if (GOK) {                 /* reload x(t+2) DIRECTLY into XREG (last use above) */  \
      XREG[0] = *(const short8*)(PXL);       XREG[1] = *(const short8*)(PXL + 32);      \
      XREG[2] = *(const short8*)(PXL + 64);  XREG[3] = *(const short8*)(PXL + 96);      \
    }                                                                                   \
    PXL += step2;                                                                       \
    u32 pk01, pk23;                                                                     \
    asm("v_cvt_pk_bf16_f32 %0, %1, %2" : "=v"(pk01) : "v"(hval[0]), "v"(hval[1]));      \
    asm("v_cvt_pk_bf16_f32 %0, %1, %2" : "=v"(pk23) : "v"(hval[2]), "v"(hval[3]));      \
    *(uint2*)(hb + (NXTO) + woff) = make_uint2(pk01, pk23);                             \
    *(uint2*)(PH) = make_uint2(pk01, pk23);                                             \
    PH += step2;                                                                        \
    asm volatile("s_waitcnt lgkmcnt(0)" ::: "memory");                                  \
    __builtin_amdgcn_s_barrier();                                                       \
    asm volatile("" ::: "memory");                                                      \
  } while (0)

  for (int tt = 0; tt < 256; tt++) {
    int gok = (tt < 255);
    HSTEP(xA, 0, 4096, pxA, phA, gok);      // step t = 2*tt
    HSTEP(xB, 4096, 0, pxB, phB, gok);      // step t = 2*tt+1
  }
#undef HSTEP
}

// ---------------- attention + FC + argmax, single pass over hs ----------------------
__global__ __launch_bounds__(512) void k_attn(const u16* __restrict__ hsf,
                                              const u16* __restrict__ hsb,
                                              const float* __restrict__ att_w,
                                              const float* __restrict__ fc_w,
                                              const float* __restrict__ fc_b,
                                              float* __restrict__ out) {
  __shared__ float rsum[8][128];
  __shared__ float esums[8];
  __shared__ float hstar[128];
  __shared__ float lg[NCLS];
  int tid = threadIdx.x, b = blockIdx.x;
  int w = tid >> 6, l = tid & 63;
  float2 aw = *(const float2*)(att_w + 2 * l);
  float r0 = 0.f, r1 = 0.f, es = 0.f;
  for (int t = w; t < T_LEN; t += 8) {
    size_t o = ((size_t)t * 128 + b) * 128 + 2 * l;
    u32 vf = *(const u32*)(hsf + o);
    u32 vb = *(const u32*)(hsb + o);
    float h0 = bf2f((u16)vf) + bf2f((u16)vb);
    float h1 = bf2f((u16)(vf >> 16)) + bf2f((u16)(vb >> 16));
    float e0 = ex2(h0 * TL2E);
    float th0 = (e0 - 1.f) * rcp_f(e0 + 1.f);
    float e1 = ex2(h1 * TL2E);
    float th1 = (e1 - 1.f) * rcp_f(e1 + 1.f);
    float s = fmaf(th0, aw.x, th1 * aw.y);
#pragma unroll
    for (int o2 = 32; o2 >= 1; o2 >>= 1) s += __shfl_xor(s, o2, 64);
    float e = ex2(s * L2E);      // no max-subtraction: |s| bounded, e^s safe in f32
    r0 = fmaf(e, h0, r0); r1 = fmaf(e, h1, r1); es += e;
  }
  rsum[w][2 * l] = r0;
  rsum[w][2 * l + 1] = r1;
  if (l == 0) esums[w] = es;
  __syncthreads();
  if (tid < 128) {
    float r = 0.f, et = 0.f;
#pragma unroll
    for (int i = 0; i < 8; i++) { r += rsum[i][tid]; et += esums[i]; }
    float rr = r / et;
    float e2 = ex2(rr * TL2E);
    hstar[tid] = (e2 - 1.f) * rcp_f(e2 + 1.f);
  }
  __syncthreads();
  if (tid < NCLS) {
    float acc = fc_b[tid];
#pragma unroll 4
    for (int hh = 0; hh < 128; hh++) acc = fmaf(hstar[hh], fc_w[hh * NCLS + tid], acc);
    out[b * NCLS + tid] = acc;
    lg[tid] = acc;
  }
  __syncthreads();
  if (tid == 0) {
    int best = 0; float bv = lg[0];
    for (int l2 = 1; l2 < NCLS; l2++)
      if (lg[l2] > bv) { bv = lg[l2]; best = l2; }
    out[2432 + b] = (float)best;   // predict_label_ids
    out[2561 + b] = (float)best;   // probabilities (argmax of softmax == argmax)
  }
}

// ---------------- l2 loss ----------------------------------------------------------
__global__ __launch_bounds__(256) void k_l2(const float* __restrict__ fc_w,
                                            const float* __restrict__ fc_b,
                                            float* __restrict__ out) {
  __shared__ float red[256];
  int tid = threadIdx.x;
  float a = 0.f;
  for (int i = tid; i < 128 * NCLS; i += 256) a += fc_w[i] * fc_w[i];
  if (tid < NCLS) a += fc_b[tid] * fc_b[tid];
  red[tid] = a; __syncthreads();
  for (int s = 128; s >= 1; s >>= 1) {
    if (tid < s) red[tid] += red[tid + s];
    __syncthreads();
  }
  if (tid == 0) out[2560] = 0.5f * red[0];
}

extern "C" void kernel_launch(void* const* d_in, const int* in_sizes, int n_in,
                              void* d_out, int out_size, void* d_ws, size_t ws_size,
                              hipStream_t stream) {
  const int* ids = (const int*)d_in[0];
  const float* table = (const float*)d_in[1];
  const float* fw_k = (const float*)d_in[2];
  const float* fw_b = (const float*)d_in[3];
  const float* bw_k = (const float*)d_in[4];
  const float* bw_b = (const float*)d_in[5];
  const float* att_w = (const float*)d_in[6];
  const float* fc_w = (const float*)d_in[7];
  const float* fc_b = (const float*)d_in[8];
  float* out = (float*)d_out;
  char* ws = (char*)d_ws;

  u16* xs = (u16*)(ws + 0);                    // 16,777,216 B   xs[t*128+b][128] bf16
  u16* wt_bf = (u16*)(ws + 16777216);          //    524,288 B   [2][512][256] bf16
  float* bias_pre = (float*)(ws + 17301504);   //      4,096 B
  u16* hs_fw = (u16*)(ws + 17305600);          // 16,777,216 B   [t][b][u] bf16
  u16* hs_bw = (u16*)(ws + 34082816);          // 16,777,216 B   (end 50,860,032)

  hipLaunchKernelGGL(k_embed, dim3(8192), dim3(256), 0, stream, ids, table, xs);
  hipLaunchKernelGGL(k_prep, dim3(1025), dim3(256), 0, stream, fw_k, bw_k, fw_b, bw_b,
                     wt_bf, bias_pre);
  hipLaunchKernelGGL(k_lstm, dim3(16), dim3(512), 0, stream, wt_bf, bias_pre, xs,
                     hs_fw, hs_bw);
  hipLaunchKernelGGL(k_attn, dim3(128), dim3(512), 0, stream, hs_fw, hs_bw, att_w,
                     fc_w, fc_b, out);
  hipLaunchKernelGGL(k_l2, dim3(1), dim3(256), 0, stream, fc_w, fc_b, out);
}

// Round 10
// 584.082 us; speedup vs baseline: 1.4752x; 1.0736x over previous
//
#include <hip/hip_runtime.h>

typedef unsigned short u16;
typedef unsigned int u32;
typedef short short8 __attribute__((ext_vector_type(8)));
typedef float f32x4 __attribute__((ext_vector_type(4)));

#define T_LEN 512
#define NCLS 19

#define L2E 1.4426950408889634f
#define TL2E 2.8853901617765067f

static __device__ __forceinline__ u16 f2bf(float f) {
  u32 u = __float_as_uint(f);
  u32 r = (u + 0x7FFFu + ((u >> 16) & 1u)) >> 16;
  return (u16)r;
}
static __device__ __forceinline__ float bf2f(u16 h) {
  return __uint_as_float(((u32)h) << 16);
}
static __device__ __forceinline__ float rcp_f(float x) { return __builtin_amdgcn_rcpf(x); }
static __device__ __forceinline__ float ex2(float x) { return __builtin_amdgcn_exp2f(x); }

// ---------------- embedding gather + cast to bf16, layout xs[t*B+b][d] -------------
__global__ __launch_bounds__(256) void k_embed(const int* __restrict__ ids,
                                               const float* __restrict__ table,
                                               u16* __restrict__ xs) {
  int i = blockIdx.x * 256 + threadIdx.x;
  int e = i * 4;               // element index, total T*B*D = 8388608
  int m = e >> 7;              // row = t*B + b
  int col = e & 127;
  int t = m >> 7, b = m & 127;
  int id = ids[b * T_LEN + t];
  float4 v = *(const float4*)(table + (size_t)id * 128 + col);
  ushort4 o;
  o.x = f2bf(v.x); o.y = f2bf(v.y); o.z = f2bf(v.z); o.w = f2bf(v.w);
  *(ushort4*)(xs + (size_t)m * 128 + col) = o;
}

// ---------------- weight prep (r5/r9-proven, UNCHANGED) ----------------------------
// p = w*64 + nt*16 + g4*4 + q  <->  unit u = w*16 + g4*4 + nt, gate q; col j = q*128+u.
// Weights pre-scaled by log2e (2*log2e for q==1); bias includes forget +1, scaled.
__global__ __launch_bounds__(256) void k_prep(const float* __restrict__ fw_k,
                                              const float* __restrict__ bw_k,
                                              const float* __restrict__ fw_b,
                                              const float* __restrict__ bw_b,
                                              u16* __restrict__ wt_bf,
                                              float* __restrict__ bias_pre) {
  int wg = blockIdx.x;
  int tid = threadIdx.x;
  if (wg < 1024) {
    int i = wg * 256 + tid;
    int n = i >> 8, k = i & 255;
    int dir = n >> 9, p = n & 511;
    int w = p >> 6, nt = (p >> 4) & 3, g4 = (p >> 2) & 3, q = p & 3;
    int u = w * 16 + g4 * 4 + nt;
    int j = q * 128 + u;
    float sc = (q == 1) ? TL2E : L2E;
    const float* K = dir ? bw_k : fw_k;
    wt_bf[i] = f2bf(K[k * 512 + j] * sc);
  } else {
    for (int uu = 0; uu < 4; uu++) {
      int n = uu * 256 + tid;
      int dir = n >> 9, p = n & 511;
      int w = p >> 6, nt = (p >> 4) & 3, g4 = (p >> 2) & 3, q = p & 3;
      int u = w * 16 + g4 * 4 + nt;
      int j = q * 128 + u;
      float sc = (q == 1) ? TL2E : L2E;
      float bv = (dir ? bw_b : fw_b)[j] + (q == 2 ? 1.0f : 0.0f);
      bias_pre[n] = bv * sc;
    }
  }
}

// ---------------- fused LSTM: 64 WGs (dir x 4-batch group), z-redistributed --------
// MFMA machinery identical to the PASSING r9 (wf layout, bias4, B-frag roles, 8-MFMA
// chain). Only 4 batches per WG -> MFMA cols 4..15 compute duplicates (discarded).
// z goes through LDS so ALL 512 threads do exactly one unit's activation (8 trans).
__global__ __launch_bounds__(512, 2) void k_lstm(const u16* __restrict__ wt_bf,
                                                 const float* __restrict__ bias_pre,
                                                 const u16* __restrict__ xs,
                                                 u16* __restrict__ hs_fw,
                                                 u16* __restrict__ hs_bw) {
  __shared__ u16 hbuf[2][4][128];     // double-buffered h, plain layout
  __shared__ float zbuf[4][512];      // z exchange: [batch][gate-row p]
  int tid = threadIdx.x;
  int wg = blockIdx.x;
  int dir = wg >> 5;
  int bb = (wg & 31) * 4;             // batch base (4 per WG)
  int w = tid >> 6, l = tid & 63;
  int cb = l & 15, g4 = l >> 4;
  int cbv = cb & 3;                   // valid-batch index (cols 4..15 duplicate)

  // resident A-frags: W^T full K=256 (128 regs -> AGPRs), r9-verbatim indices
  short8 wf[32];
#pragma unroll
  for (int n = 0; n < 4; n++) {
    const u16* wb = wt_bf + ((size_t)(dir * 512 + w * 64 + n * 16 + cb) * 256) + g4 * 8;
#pragma unroll
    for (int ks = 0; ks < 8; ks++)
      wf[n * 8 + ks] = *(const short8*)(wb + ks * 32);
  }
  f32x4 bias4[4];
#pragma unroll
  for (int n = 0; n < 4; n++)
    bias4[n] = *(const f32x4*)(bias_pre + dir * 512 + w * 64 + n * 16 + g4 * 4);

  // activation ownership: thread -> (batch cbl, unit u)
  int cbl = tid >> 7;                 // 0..3
  int un = tid & 127;                 // unit
  int p0 = (un >> 4) * 64 + (un & 3) * 16 + ((un >> 2) & 3) * 4;  // gate rows p0..p0+3
  float c = 0.0f;

  int roff[4];
#pragma unroll
  for (int ks = 0; ks < 4; ks++)
    roff[ks] = cbv * 256 + ks * 64 + g4 * 16;   // bytes into a hbuf slot (row=256B)
  int zoff = w * 64 + g4 * 4;                   // + n*16 at write time

  // zero both h buffers (h(0)=0)
  ((u32*)hbuf)[tid] = 0;              // 2*4*128 u16 = 512 u32
  __syncthreads();

  int t0a = dir ? (T_LEN - 1) : 0;
  int stp = dir ? -1 : 1;
  u16* hsout = dir ? hs_bw : hs_fw;
  long step1 = (long)stp * 16384;     // one time step, elements
  long step2 = 2 * step1;

  const u16* xbase = xs + ((size_t)(t0a * 128 + bb + cbv) * 128) + g4 * 8;
  u16* ph = hsout + ((size_t)(t0a * 128 + bb + cbl) * 128) + un;

  short8 xA[4], xB[4];
#pragma unroll
  for (int ks = 0; ks < 4; ks++) xA[ks] = *(const short8*)(xbase + ks * 32);        // x(0)
  const u16* pxB0 = xbase + step1;
#pragma unroll
  for (int ks = 0; ks < 4; ks++) xB[ks] = *(const short8*)(pxB0 + ks * 32);         // x(1)
  const u16* pxA = xbase + step2;     // reloads x(t+2), t even
  const u16* pxB = pxB0 + step2;      // reloads x(t+2), t odd

#define HSTEP(XREG, CUR, NXT, PXL, GOK)                                                 \
  do {                                                                                  \
    const char* hrow = (const char*)&hbuf[CUR][0][0];                                   \
    short8 hf0 = *(const short8*)(hrow + roff[0]);                                      \
    short8 hf1 = *(const short8*)(hrow + roff[1]);                                      \
    short8 hf2 = *(const short8*)(hrow + roff[2]);                                      \
    short8 hf3 = *(const short8*)(hrow + roff[3]);                                      \
    _Pragma("unroll")                                                                   \
    for (int n = 0; n < 4; n++) {                                                       \
      f32x4 acc = bias4[n];                                                             \
      acc = __builtin_amdgcn_mfma_f32_16x16x32_bf16(wf[n * 8 + 0], XREG[0], acc, 0,0,0);\
      acc = __builtin_amdgcn_mfma_f32_16x16x32_bf16(wf[n * 8 + 1], XREG[1], acc, 0,0,0);\
      acc = __builtin_amdgcn_mfma_f32_16x16x32_bf16(wf[n * 8 + 2], XREG[2], acc, 0,0,0);\
      acc = __builtin_amdgcn_mfma_f32_16x16x32_bf16(wf[n * 8 + 3], XREG[3], acc, 0,0,0);\
      acc = __builtin_amdgcn_mfma_f32_16x16x32_bf16(wf[n * 8 + 4], hf0, acc, 0, 0, 0);  \
      acc = __builtin_amdgcn_mfma_f32_16x16x32_bf16(wf[n * 8 + 5], hf1, acc, 0, 0, 0);  \
      acc = __builtin_amdgcn_mfma_f32_16x16x32_bf16(wf[n * 8 + 6], hf2, acc, 0, 0, 0);  \
      acc = __builtin_amdgcn_mfma_f32_16x16x32_bf16(wf[n * 8 + 7], hf3, acc, 0, 0, 0);  \
      if (cb < 4) *(f32x4*)&zbuf[cb][zoff + n * 16] = acc;                              \
    }                                                                                   \
    if (GOK) {                 /* reload x(t+2) DIRECTLY into XREG (last use above) */  \
      XREG[0] = *(const short8*)(PXL);       XREG[1] = *(const short8*)(PXL + 32);      \
      XREG[2] = *(const short8*)(PXL + 64);  XREG[3] = *(const short8*)(PXL + 96);      \
    }                                                                                   \
    PXL += step2;                                                                       \
    asm volatile("s_waitcnt lgkmcnt(0)" ::: "memory");                                  \
    __builtin_amdgcn_s_barrier();                                                       \
    asm volatile("" ::: "memory");                                                      \
    f32x4 z = *(const f32x4*)&zbuf[cbl][p0];                                            \
    float A2 = ex2(-z[0]);                 /* e^-zi           */                        \
    float B2 = ex2(z[1]);                  /* e^{2zj}         */                        \
    float F2 = ex2(-z[2]);                 /* e^-(zf+1)       */                        \
    float O2 = ex2(-z[3]);                 /* e^-zo           */                        \
    float r1 = rcp_f((1.f + A2) * (1.f + B2));                                          \
    float rf = rcp_f(1.f + F2);                                                         \
    float cn = fmaf(c, rf, (B2 - 1.f) * r1);                                            \
    c = cn;                                                                             \
    float C2 = ex2(cn * TL2E);             /* e^{2c}          */                        \
    float r2 = rcp_f((1.f + C2) * (1.f + O2));                                          \
    float hv = (C2 - 1.f) * r2;            /* tanh(c)*sig(zo) */                        \
    u16 hb16 = f2bf(hv);                                                                \
    hbuf[NXT][cbl][un] = hb16;                                                          \
    *ph = hb16;                                                                         \
    ph += step1;                                                                        \
    asm volatile("s_waitcnt lgkmcnt(0)" ::: "memory");                                  \
    __builtin_amdgcn_s_barrier();                                                       \
    asm volatile("" ::: "memory");                                                      \
  } while (0)

  for (int tt = 0; tt < 256; tt++) {
    int gok = (tt < 255);
    HSTEP(xA, 0, 1, pxA, gok);      // step t = 2*tt
    HSTEP(xB, 1, 0, pxB, gok);      // step t = 2*tt+1
  }
#undef HSTEP
}

// ---------------- attention + FC + argmax, single pass over hs ----------------------
__global__ __launch_bounds__(512) void k_attn(const u16* __restrict__ hsf,
                                              const u16* __restrict__ hsb,
                                              const float* __restrict__ att_w,
                                              const float* __restrict__ fc_w,
                                              const float* __restrict__ fc_b,
                                              float* __restrict__ out) {
  __shared__ float rsum[8][128];
  __shared__ float esums[8];
  __shared__ float hstar[128];
  __shared__ float lg[NCLS];
  int tid = threadIdx.x, b = blockIdx.x;
  int w = tid >> 6, l = tid & 63;
  float2 aw = *(const float2*)(att_w + 2 * l);
  float r0 = 0.f, r1 = 0.f, es = 0.f;
  for (int t = w; t < T_LEN; t += 8) {
    size_t o = ((size_t)t * 128 + b) * 128 + 2 * l;
    u32 vf = *(const u32*)(hsf + o);
    u32 vb = *(const u32*)(hsb + o);
    float h0 = bf2f((u16)vf) + bf2f((u16)vb);
    float h1 = bf2f((u16)(vf >> 16)) + bf2f((u16)(vb >> 16));
    float e0 = ex2(h0 * TL2E);
    float th0 = (e0 - 1.f) * rcp_f(e0 + 1.f);
    float e1 = ex2(h1 * TL2E);
    float th1 = (e1 - 1.f) * rcp_f(e1 + 1.f);
    float s = fmaf(th0, aw.x, th1 * aw.y);
#pragma unroll
    for (int o2 = 32; o2 >= 1; o2 >>= 1) s += __shfl_xor(s, o2, 64);
    float e = ex2(s * L2E);      // no max-subtraction: |s| bounded, e^s safe in f32
    r0 = fmaf(e, h0, r0); r1 = fmaf(e, h1, r1); es += e;
  }
  rsum[w][2 * l] = r0;
  rsum[w][2 * l + 1] = r1;
  if (l == 0) esums[w] = es;
  __syncthreads();
  if (tid < 128) {
    float r = 0.f, et = 0.f;
#pragma unroll
    for (int i = 0; i < 8; i++) { r += rsum[i][tid]; et += esums[i]; }
    float rr = r / et;
    float e2 = ex2(rr * TL2E);
    hstar[tid] = (e2 - 1.f) * rcp_f(e2 + 1.f);
  }
  __syncthreads();
  if (tid < NCLS) {
    float acc = fc_b[tid];
#pragma unroll 4
    for (int hh = 0; hh < 128; hh++) acc = fmaf(hstar[hh], fc_w[hh * NCLS + tid], acc);
    out[b * NCLS + tid] = acc;
    lg[tid] = acc;
  }
  __syncthreads();
  if (tid == 0) {
    int best = 0; float bv = lg[0];
    for (int l2 = 1; l2 < NCLS; l2++)
      if (lg[l2] > bv) { bv = lg[l2]; best = l2; }
    out[2432 + b] = (float)best;   // predict_label_ids
    out[2561 + b] = (float)best;   // probabilities (argmax of softmax == argmax)
  }
}

// ---------------- l2 loss ----------------------------------------------------------
__global__ __launch_bounds__(256) void k_l2(const float* __restrict__ fc_w,
                                            const float* __restrict__ fc_b,
                                            float* __restrict__ out) {
  __shared__ float red[256];
  int tid = threadIdx.x;
  float a = 0.f;
  for (int i = tid; i < 128 * NCLS; i += 256) a += fc_w[i] * fc_w[i];
  if (tid < NCLS) a += fc_b[tid] * fc_b[tid];
  red[tid] = a; __syncthreads();
  for (int s = 128; s >= 1; s >>= 1) {
    if (tid < s) red[tid] += red[tid + s];
    __syncthreads();
  }
  if (tid == 0) out[2560] = 0.5f * red[0];
}

extern "C" void kernel_launch(void* const* d_in, const int* in_sizes, int n_in,
                              void* d_out, int out_size, void* d_ws, size_t ws_size,
                              hipStream_t stream) {
  const int* ids = (const int*)d_in[0];
  const float* table = (const float*)d_in[1];
  const float* fw_k = (const float*)d_in[2];
  const float* fw_b = (const float*)d_in[3];
  const float* bw_k = (const float*)d_in[4];
  const float* bw_b = (const float*)d_in[5];
  const float* att_w = (const float*)d_in[6];
  const float* fc_w = (const float*)d_in[7];
  const float* fc_b = (const float*)d_in[8];
  float* out = (float*)d_out;
  char* ws = (char*)d_ws;

  u16* xs = (u16*)(ws + 0);                    // 16,777,216 B   xs[t*128+b][128] bf16
  u16* wt_bf = (u16*)(ws + 16777216);          //    524,288 B   [2][512][256] bf16
  float* bias_pre = (float*)(ws + 17301504);   //      4,096 B
  u16* hs_fw = (u16*)(ws + 17305600);          // 16,777,216 B   [t][b][u] bf16
  u16* hs_bw = (u16*)(ws + 34082816);          // 16,777,216 B   (end 50,860,032)

  hipLaunchKernelGGL(k_embed, dim3(8192), dim3(256), 0, stream, ids, table, xs);
  hipLaunchKernelGGL(k_prep, dim3(1025), dim3(256), 0, stream, fw_k, bw_k, fw_b, bw_b,
                     wt_bf, bias_pre);
  hipLaunchKernelGGL(k_lstm, dim3(64), dim3(512), 0, stream, wt_bf, bias_pre, xs,
                     hs_fw, hs_bw);
  hipLaunchKernelGGL(k_attn, dim3(128), dim3(512), 0, stream, hs_fw, hs_bw, att_w,
                     fc_w, fc_b, out);
  hipLaunchKernelGGL(k_l2, dim3(1), dim3(256), 0, stream, fc_w, fc_b, out);
}

// Round 11
// 518.215 us; speedup vs baseline: 1.6627x; 1.1271x over previous
//
#include <hip/hip_runtime.h>

typedef unsigned short u16;
typedef unsigned int u32;
typedef short short8 __attribute__((ext_vector_type(8)));
typedef float f32x4 __attribute__((ext_vector_type(4)));

#define T_LEN 512
#define NCLS 19

#define L2E 1.4426950408889634f
#define TL2E 2.8853901617765067f

static __device__ __forceinline__ u16 f2bf(float f) {
  u32 u = __float_as_uint(f);
  u32 r = (u + 0x7FFFu + ((u >> 16) & 1u)) >> 16;
  return (u16)r;
}
static __device__ __forceinline__ float bf2f(u16 h) {
  return __uint_as_float(((u32)h) << 16);
}
static __device__ __forceinline__ float rcp_f(float x) { return __builtin_amdgcn_rcpf(x); }
static __device__ __forceinline__ float ex2(float x) { return __builtin_amdgcn_exp2f(x); }

// ---------------- embedding gather + cast to bf16, layout xs[t*B+b][d] -------------
__global__ __launch_bounds__(256) void k_embed(const int* __restrict__ ids,
                                               const float* __restrict__ table,
                                               u16* __restrict__ xs) {
  int i = blockIdx.x * 256 + threadIdx.x;
  int e = i * 4;               // element index, total T*B*D = 8388608
  int m = e >> 7;              // row = t*B + b
  int col = e & 127;
  int t = m >> 7, b = m & 127;
  int id = ids[b * T_LEN + t];
  float4 v = *(const float4*)(table + (size_t)id * 128 + col);
  ushort4 o;
  o.x = f2bf(v.x); o.y = f2bf(v.y); o.z = f2bf(v.z); o.w = f2bf(v.w);
  *(ushort4*)(xs + (size_t)m * 128 + col) = o;
}

// ---------------- weight prep (r5/r9/r10-proven, UNCHANGED) ------------------------
// p = w*64 + nt*16 + g4*4 + q  <->  unit u = w*16 + g4*4 + nt, gate q; col j = q*128+u.
// Weights pre-scaled by log2e (2*log2e for q==1); bias includes forget +1, scaled.
__global__ __launch_bounds__(256) void k_prep(const float* __restrict__ fw_k,
                                              const float* __restrict__ bw_k,
                                              const float* __restrict__ fw_b,
                                              const float* __restrict__ bw_b,
                                              u16* __restrict__ wt_bf,
                                              float* __restrict__ bias_pre) {
  int wg = blockIdx.x;
  int tid = threadIdx.x;
  if (wg < 1024) {
    int i = wg * 256 + tid;
    int n = i >> 8, k = i & 255;
    int dir = n >> 9, p = n & 511;
    int w = p >> 6, nt = (p >> 4) & 3, g4 = (p >> 2) & 3, q = p & 3;
    int u = w * 16 + g4 * 4 + nt;
    int j = q * 128 + u;
    float sc = (q == 1) ? TL2E : L2E;
    const float* K = dir ? bw_k : fw_k;
    wt_bf[i] = f2bf(K[k * 512 + j] * sc);
  } else {
    for (int uu = 0; uu < 4; uu++) {
      int n = uu * 256 + tid;
      int dir = n >> 9, p = n & 511;
      int w = p >> 6, nt = (p >> 4) & 3, g4 = (p >> 2) & 3, q = p & 3;
      int u = w * 16 + g4 * 4 + nt;
      int j = q * 128 + u;
      float sc = (q == 1) ? TL2E : L2E;
      float bv = (dir ? bw_b : fw_b)[j] + (q == 2 ? 1.0f : 0.0f);
      bias_pre[n] = bv * sc;
    }
  }
}

// ---------------- fused LSTM: 64 WGs, padded LDS + accx pre-accumulation -----------
// r10 structure; deltas: (1) zbuf rows padded to 520 floats, hbuf rows to 288 B
// (kills the 4-way bank conflicts = 768 cyc/step); (2) the 4 x-MFMAs for step t+1
// run in step t's activation phase (register-only, between barriers) so the
// post-barrier dependent chain is 4 h-MFMAs, and the MFMA pipe stays fed.
__global__ __launch_bounds__(512, 2) void k_lstm(const u16* __restrict__ wt_bf,
                                                 const float* __restrict__ bias_pre,
                                                 const u16* __restrict__ xs,
                                                 u16* __restrict__ hs_fw,
                                                 u16* __restrict__ hs_bw) {
  __shared__ u16 hbuf[2][4][144];     // double-buffered h, 288B rows (padded)
  __shared__ float zbuf[4][520];      // z exchange, padded rows
  int tid = threadIdx.x;
  int wg = blockIdx.x;
  int dir = wg >> 5;
  int bb = (wg & 31) * 4;             // batch base (4 per WG)
  int w = tid >> 6, l = tid & 63;
  int cb = l & 15, g4 = l >> 4;
  int cbv = cb & 3;                   // valid-batch index (cols 4..15 duplicate)

  // resident A-frags: W^T full K=256 (128 regs -> AGPRs), r9/r10-verbatim indices
  short8 wf[32];
#pragma unroll
  for (int n = 0; n < 4; n++) {
    const u16* wb = wt_bf + ((size_t)(dir * 512 + w * 64 + n * 16 + cb) * 256) + g4 * 8;
#pragma unroll
    for (int ks = 0; ks < 8; ks++)
      wf[n * 8 + ks] = *(const short8*)(wb + ks * 32);
  }
  f32x4 bias4[4];
#pragma unroll
  for (int n = 0; n < 4; n++)
    bias4[n] = *(const f32x4*)(bias_pre + dir * 512 + w * 64 + n * 16 + g4 * 4);

  // activation ownership: thread -> (batch cbl, unit un)
  int cbl = tid >> 7;                 // 0..3
  int un = tid & 127;                 // unit
  int p0 = (un >> 4) * 64 + (un & 3) * 16 + ((un >> 2) & 3) * 4;  // gate rows p0..p0+3
  float c = 0.0f;

  int roff[4];
#pragma unroll
  for (int ks = 0; ks < 4; ks++)
    roff[ks] = cbv * 288 + ks * 64 + g4 * 16;   // bytes into a hbuf slot (row=288B)
  int zoff = w * 64 + g4 * 4;                   // + n*16 at write time (floats)

  // zero both h buffers (h(0)=0): 2*4*144 u16 = 576 u32
  u32* hz = (u32*)hbuf;
  hz[tid >= 512 ? 0 : tid] = 0;
  if (tid < 64) hz[512 + tid] = 0;
  __syncthreads();

  int t0a = dir ? (T_LEN - 1) : 0;
  int stp = dir ? -1 : 1;
  u16* hsout = dir ? hs_bw : hs_fw;
  long step1 = (long)stp * 16384;     // one time step, elements
  long step2 = 2 * step1;

  const u16* xbase = xs + ((size_t)(t0a * 128 + bb + cbv) * 128) + g4 * 8;
  u16* ph = hsout + ((size_t)(t0a * 128 + bb + cbl) * 128) + un;

  short8 xA[4], xB[4];
#pragma unroll
  for (int ks = 0; ks < 4; ks++) xA[ks] = *(const short8*)(xbase + ks * 32);        // x(0)
  const u16* pxB0 = xbase + step1;
#pragma unroll
  for (int ks = 0; ks < 4; ks++) xB[ks] = *(const short8*)(pxB0 + ks * 32);         // x(1)

  // prologue: accx for step 0 from xA = x(0); then reload xA <- x(2)
  f32x4 accx[4];
#pragma unroll
  for (int n = 0; n < 4; n++) {
    f32x4 acc = bias4[n];
    acc = __builtin_amdgcn_mfma_f32_16x16x32_bf16(wf[n * 8 + 0], xA[0], acc, 0, 0, 0);
    acc = __builtin_amdgcn_mfma_f32_16x16x32_bf16(wf[n * 8 + 1], xA[1], acc, 0, 0, 0);
    acc = __builtin_amdgcn_mfma_f32_16x16x32_bf16(wf[n * 8 + 2], xA[2], acc, 0, 0, 0);
    acc = __builtin_amdgcn_mfma_f32_16x16x32_bf16(wf[n * 8 + 3], xA[3], acc, 0, 0, 0);
    accx[n] = acc;
  }
  const u16* pxA = xbase + step2;     // x(2)
#pragma unroll
  for (int ks = 0; ks < 4; ks++) xA[ks] = *(const short8*)(pxA + ks * 32);
  pxA += step2;                       // -> x(4)
  const u16* pxB = pxB0 + step2;      // x(3)

// HSTEP: consume accx (this step); between barriers build accx for NEXT step from
// XNEXT (the other buffer), then reload XNEXT (2 steps of slack before next use).
#define HSTEP(CUR, NXT, XNEXT, PXL, GOK)                                                \
  do {                                                                                  \
    const char* hrow = (const char*)&hbuf[CUR][0][0];                                   \
    short8 hf0 = *(const short8*)(hrow + roff[0]);                                      \
    short8 hf1 = *(const short8*)(hrow + roff[1]);                                      \
    short8 hf2 = *(const short8*)(hrow + roff[2]);                                      \
    short8 hf3 = *(const short8*)(hrow + roff[3]);                                      \
    _Pragma("unroll")                                                                   \
    for (int n = 0; n < 4; n++) {                                                       \
      f32x4 acc = accx[n];                                                              \
      acc = __builtin_amdgcn_mfma_f32_16x16x32_bf16(wf[n * 8 + 4], hf0, acc, 0, 0, 0);  \
      acc = __builtin_amdgcn_mfma_f32_16x16x32_bf16(wf[n * 8 + 5], hf1, acc, 0, 0, 0);  \
      acc = __builtin_amdgcn_mfma_f32_16x16x32_bf16(wf[n * 8 + 6], hf2, acc, 0, 0, 0);  \
      acc = __builtin_amdgcn_mfma_f32_16x16x32_bf16(wf[n * 8 + 7], hf3, acc, 0, 0, 0);  \
      if (cb < 4) *(f32x4*)&zbuf[cb][zoff + n * 16] = acc;                              \
    }                                                                                   \
    asm volatile("s_waitcnt lgkmcnt(0)" ::: "memory");                                  \
    __builtin_amdgcn_s_barrier();                                                       \
    asm volatile("" ::: "memory");                                                      \
    _Pragma("unroll")                                                                   \
    for (int n = 0; n < 4; n++) {           /* accx for next step (register-only) */    \
      f32x4 acc = bias4[n];                                                             \
      acc = __builtin_amdgcn_mfma_f32_16x16x32_bf16(wf[n * 8 + 0], XNEXT[0], acc, 0,0,0);\
      acc = __builtin_amdgcn_mfma_f32_16x16x32_bf16(wf[n * 8 + 1], XNEXT[1], acc, 0,0,0);\
      acc = __builtin_amdgcn_mfma_f32_16x16x32_bf16(wf[n * 8 + 2], XNEXT[2], acc, 0,0,0);\
      acc = __builtin_amdgcn_mfma_f32_16x16x32_bf16(wf[n * 8 + 3], XNEXT[3], acc, 0,0,0);\
      accx[n] = acc;                                                                    \
    }                                                                                   \
    if (GOK) {                              /* reload XNEXT, 2 steps of slack */        \
      XNEXT[0] = *(const short8*)(PXL);       XNEXT[1] = *(const short8*)(PXL + 32);    \
      XNEXT[2] = *(const short8*)(PXL + 64);  XNEXT[3] = *(const short8*)(PXL + 96);    \
    }                                                                                   \
    PXL += step2;                                                                       \
    f32x4 z = *(const f32x4*)&zbuf[cbl][p0];                                            \
    float A2 = ex2(-z[0]);                 /* e^-zi           */                        \
    float B2 = ex2(z[1]);                  /* e^{2zj}         */                        \
    float F2 = ex2(-z[2]);                 /* e^-(zf+1)       */                        \
    float O2 = ex2(-z[3]);                 /* e^-zo           */                        \
    float r1 = rcp_f((1.f + A2) * (1.f + B2));                                          \
    float rf = rcp_f(1.f + F2);                                                         \
    float cn = fmaf(c, rf, (B2 - 1.f) * r1);                                            \
    c = cn;                                                                             \
    float C2 = ex2(cn * TL2E);             /* e^{2c}          */                        \
    float r2 = rcp_f((1.f + C2) * (1.f + O2));                                          \
    float hv = (C2 - 1.f) * r2;            /* tanh(c)*sig(zo) */                        \
    u16 hb16 = f2bf(hv);                                                                \
    hbuf[NXT][cbl][un] = hb16;                                                          \
    *ph = hb16;                                                                         \
    ph += step1;                                                                        \
    asm volatile("s_waitcnt lgkmcnt(0)" ::: "memory");                                  \
    __builtin_amdgcn_s_barrier();                                                       \
    asm volatile("" ::: "memory");                                                      \
  } while (0)

  for (int tt = 0; tt < 256; tt++) {
    HSTEP(0, 1, xB, pxB, (tt < 255));   // step t=2tt:   builds accx(2tt+1) from xB
    HSTEP(1, 0, xA, pxA, (tt < 254));   // step t=2tt+1: builds accx(2tt+2) from xA
  }
#undef HSTEP
}

// ---------------- attention + FC + argmax, single pass over hs ----------------------
__global__ __launch_bounds__(512) void k_attn(const u16* __restrict__ hsf,
                                              const u16* __restrict__ hsb,
                                              const float* __restrict__ att_w,
                                              const float* __restrict__ fc_w,
                                              const float* __restrict__ fc_b,
                                              float* __restrict__ out) {
  __shared__ float rsum[8][128];
  __shared__ float esums[8];
  __shared__ float hstar[128];
  __shared__ float lg[NCLS];
  int tid = threadIdx.x, b = blockIdx.x;
  int w = tid >> 6, l = tid & 63;
  float2 aw = *(const float2*)(att_w + 2 * l);
  float r0 = 0.f, r1 = 0.f, es = 0.f;
  for (int t = w; t < T_LEN; t += 8) {
    size_t o = ((size_t)t * 128 + b) * 128 + 2 * l;
    u32 vf = *(const u32*)(hsf + o);
    u32 vb = *(const u32*)(hsb + o);
    float h0 = bf2f((u16)vf) + bf2f((u16)vb);
    float h1 = bf2f((u16)(vf >> 16)) + bf2f((u16)(vb >> 16));
    float e0 = ex2(h0 * TL2E);
    float th0 = (e0 - 1.f) * rcp_f(e0 + 1.f);
    float e1 = ex2(h1 * TL2E);
    float th1 = (e1 - 1.f) * rcp_f(e1 + 1.f);
    float s = fmaf(th0, aw.x, th1 * aw.y);
#pragma unroll
    for (int o2 = 32; o2 >= 1; o2 >>= 1) s += __shfl_xor(s, o2, 64);
    float e = ex2(s * L2E);      // no max-subtraction: |s| bounded, e^s safe in f32
    r0 = fmaf(e, h0, r0); r1 = fmaf(e, h1, r1); es += e;
  }
  rsum[w][2 * l] = r0;
  rsum[w][2 * l + 1] = r1;
  if (l == 0) esums[w] = es;
  __syncthreads();
  if (tid < 128) {
    float r = 0.f, et = 0.f;
#pragma unroll
    for (int i = 0; i < 8; i++) { r += rsum[i][tid]; et += esums[i]; }
    float rr = r / et;
    float e2 = ex2(rr * TL2E);
    hstar[tid] = (e2 - 1.f) * rcp_f(e2 + 1.f);
  }
  __syncthreads();
  if (tid < NCLS) {
    float acc = fc_b[tid];
#pragma unroll 4
    for (int hh = 0; hh < 128; hh++) acc = fmaf(hstar[hh], fc_w[hh * NCLS + tid], acc);
    out[b * NCLS + tid] = acc;
    lg[tid] = acc;
  }
  __syncthreads();
  if (tid == 0) {
    int best = 0; float bv = lg[0];
    for (int l2 = 1; l2 < NCLS; l2++)
      if (lg[l2] > bv) { bv = lg[l2]; best = l2; }
    out[2432 + b] = (float)best;   // predict_label_ids
    out[2561 + b] = (float)best;   // probabilities (argmax of softmax == argmax)
  }
}

// ---------------- l2 loss ----------------------------------------------------------
__global__ __launch_bounds__(256) void k_l2(const float* __restrict__ fc_w,
                                            const float* __restrict__ fc_b,
                                            float* __restrict__ out) {
  __shared__ float red[256];
  int tid = threadIdx.x;
  float a = 0.f;
  for (int i = tid; i < 128 * NCLS; i += 256) a += fc_w[i] * fc_w[i];
  if (tid < NCLS) a += fc_b[tid] * fc_b[tid];
  red[tid] = a; __syncthreads();
  for (int s = 128; s >= 1; s >>= 1) {
    if (tid < s) red[tid] += red[tid + s];
    __syncthreads();
  }
  if (tid == 0) out[2560] = 0.5f * red[0];
}

extern "C" void kernel_launch(void* const* d_in, const int* in_sizes, int n_in,
                              void* d_out, int out_size, void* d_ws, size_t ws_size,
                              hipStream_t stream) {
  const int* ids = (const int*)d_in[0];
  const float* table = (const float*)d_in[1];
  const float* fw_k = (const float*)d_in[2];
  const float* fw_b = (const float*)d_in[3];
  const float* bw_k = (const float*)d_in[4];
  const float* bw_b = (const float*)d_in[5];
  const float* att_w = (const float*)d_in[6];
  const float* fc_w = (const float*)d_in[7];
  const float* fc_b = (const float*)d_in[8];
  float* out = (float*)d_out;
  char* ws = (char*)d_ws;

  u16* xs = (u16*)(ws + 0);                    // 16,777,216 B   xs[t*128+b][128] bf16
  u16* wt_bf = (u16*)(ws + 16777216);          //    524,288 B   [2][512][256] bf16
  float* bias_pre = (float*)(ws + 17301504);   //      4,096 B
  u16* hs_fw = (u16*)(ws + 17305600);          // 16,777,216 B   [t][b][u] bf16
  u16* hs_bw = (u16*)(ws + 34082816);          // 16,777,216 B   (end 50,860,032)

  hipLaunchKernelGGL(k_embed, dim3(8192), dim3(256), 0, stream, ids, table, xs);
  hipLaunchKernelGGL(k_prep, dim3(1025), dim3(256), 0, stream, fw_k, bw_k, fw_b, bw_b,
                     wt_bf, bias_pre);
  hipLaunchKernelGGL(k_lstm, dim3(64), dim3(512), 0, stream, wt_bf, bias_pre, xs,
                     hs_fw, hs_bw);
  hipLaunchKernelGGL(k_attn, dim3(128), dim3(512), 0, stream, hs_fw, hs_bw, att_w,
                     fc_w, fc_b, out);
  hipLaunchKernelGGL(k_l2, dim3(1), dim3(256), 0, stream, fc_w, fc_b, out);
}

// Round 12
// 470.485 us; speedup vs baseline: 1.8314x; 1.1014x over previous
//
#include <hip/hip_runtime.h>

typedef unsigned short u16;
typedef unsigned int u32;
typedef short short8 __attribute__((ext_vector_type(8)));
typedef float f32x4 __attribute__((ext_vector_type(4)));

#define T_LEN 512
#define NCLS 19

#define L2E 1.4426950408889634f
#define TL2E 2.8853901617765067f

static __device__ __forceinline__ u16 f2bf(float f) {
  u32 u = __float_as_uint(f);
  u32 r = (u + 0x7FFFu + ((u >> 16) & 1u)) >> 16;
  return (u16)r;
}
static __device__ __forceinline__ float bf2f(u16 h) {
  return __uint_as_float(((u32)h) << 16);
}
static __device__ __forceinline__ float rcp_f(float x) { return __builtin_amdgcn_rcpf(x); }
static __device__ __forceinline__ float ex2(float x) { return __builtin_amdgcn_exp2f(x); }

// ---------------- embedding gather + cast to bf16, layout xs[t*B+b][d] -------------
__global__ __launch_bounds__(256) void k_embed(const int* __restrict__ ids,
                                               const float* __restrict__ table,
                                               u16* __restrict__ xs) {
  int i = blockIdx.x * 256 + threadIdx.x;
  int e = i * 4;               // element index, total T*B*D = 8388608
  int m = e >> 7;              // row = t*B + b
  int col = e & 127;
  int t = m >> 7, b = m & 127;
  int id = ids[b * T_LEN + t];
  float4 v = *(const float4*)(table + (size_t)id * 128 + col);
  ushort4 o;
  o.x = f2bf(v.x); o.y = f2bf(v.y); o.z = f2bf(v.z); o.w = f2bf(v.w);
  *(ushort4*)(xs + (size_t)m * 128 + col) = o;
}

// ---------------- weight prep (r5/r9/r11-proven, UNCHANGED) ------------------------
// p = w*64 + nt*16 + g4*4 + q  <->  unit u = w*16 + g4*4 + nt, gate q; col j = q*128+u.
// Weights pre-scaled by log2e (2*log2e for q==1); bias includes forget +1, scaled.
__global__ __launch_bounds__(256) void k_prep(const float* __restrict__ fw_k,
                                              const float* __restrict__ bw_k,
                                              const float* __restrict__ fw_b,
                                              const float* __restrict__ bw_b,
                                              u16* __restrict__ wt_bf,
                                              float* __restrict__ bias_pre) {
  int wg = blockIdx.x;
  int tid = threadIdx.x;
  if (wg < 1024) {
    int i = wg * 256 + tid;
    int n = i >> 8, k = i & 255;
    int dir = n >> 9, p = n & 511;
    int w = p >> 6, nt = (p >> 4) & 3, g4 = (p >> 2) & 3, q = p & 3;
    int u = w * 16 + g4 * 4 + nt;
    int j = q * 128 + u;
    float sc = (q == 1) ? TL2E : L2E;
    const float* K = dir ? bw_k : fw_k;
    wt_bf[i] = f2bf(K[k * 512 + j] * sc);
  } else {
    for (int uu = 0; uu < 4; uu++) {
      int n = uu * 256 + tid;
      int dir = n >> 9, p = n & 511;
      int w = p >> 6, nt = (p >> 4) & 3, g4 = (p >> 2) & 3, q = p & 3;
      int u = w * 16 + g4 * 4 + nt;
      int j = q * 128 + u;
      float sc = (q == 1) ? TL2E : L2E;
      float bv = (dir ? bw_b : fw_b)[j] + (q == 2 ? 1.0f : 0.0f);
      bias_pre[n] = bv * sc;
    }
  }
}

// ---------------- fused LSTM: 64 WGs, 4-step-batched x-projection ------------------
// r11 structure (padded zbuf/hbuf, z-redistributed activation, 2 barriers/step).
// Delta: per-step x-MFMAs (16/wave, 4x duplicated) replaced by ONE x-block every 4
// steps whose MFMA columns = (step-offset so, batch cbv) — all 16 distinct, no waste.
// Results staged in padded xstage[16][520] f32 LDS; per-step acc-init is a broadcast
// f32x4 LDS read. In-loop MFMA: 32 -> 20 per wave per step (amortized).
__global__ __launch_bounds__(512, 2) void k_lstm(const u16* __restrict__ wt_bf,
                                                 const float* __restrict__ bias_pre,
                                                 const u16* __restrict__ xs,
                                                 u16* __restrict__ hs_fw,
                                                 u16* __restrict__ hs_bw) {
  __shared__ u16 hbuf[2][4][144];     // double-buffered h, 288B rows (padded, r11)
  __shared__ float zbuf[4][520];      // z exchange, padded rows (r11)
  __shared__ float xstage[16][520];   // z_x for 4 steps: row = so*4+cbv, col = gate p
  int tid = threadIdx.x;
  int wg = blockIdx.x;
  int dir = wg >> 5;
  int bb = (wg & 31) * 4;             // batch base (4 per WG)
  int w = tid >> 6, l = tid & 63;
  int cb = l & 15, g4 = l >> 4;
  int cbv = cb & 3;                   // batch index within group
  int so = cb >> 2;                   // step-offset role of this lane in the x-block

  // resident A-frags: W^T full K=256 (128 regs -> AGPRs), r9/r11-verbatim indices
  short8 wf[32];
#pragma unroll
  for (int n = 0; n < 4; n++) {
    const u16* wb = wt_bf + ((size_t)(dir * 512 + w * 64 + n * 16 + cb) * 256) + g4 * 8;
#pragma unroll
    for (int ks = 0; ks < 8; ks++)
      wf[n * 8 + ks] = *(const short8*)(wb + ks * 32);
  }
  f32x4 bias4[4];
#pragma unroll
  for (int n = 0; n < 4; n++)
    bias4[n] = *(const f32x4*)(bias_pre + dir * 512 + w * 64 + n * 16 + g4 * 4);

  // activation ownership: thread -> (batch cbl, unit un)   (r11-verbatim)
  int cbl = tid >> 7;                 // 0..3
  int un = tid & 127;                 // unit
  int p0 = (un >> 4) * 64 + (un & 3) * 16 + ((un >> 2) & 3) * 4;
  float c = 0.0f;

  int roff[4];
#pragma unroll
  for (int ks = 0; ks < 4; ks++)
    roff[ks] = cbv * 288 + ks * 64 + g4 * 16;   // bytes into a hbuf slot (row=288B)
  int zoff = w * 64 + g4 * 4;                   // + n*16 at write time (floats)
  int xcol = w * 256 + g4 * 16;                 // byte offset within an xstage row: + n*64

  // zero both h buffers (h(0)=0): 2*4*144 u16 = 576 u32
  u32* hz = (u32*)hbuf;
  hz[tid >= 512 ? 0 : tid] = 0;
  if (tid < 64) hz[512 + tid] = 0;
  __syncthreads();

  int t0a = dir ? (T_LEN - 1) : 0;
  int stp = dir ? -1 : 1;
  u16* hsout = dir ? hs_bw : hs_fw;
  long step1 = (long)stp * 16384;     // one time step, elements

  const u16* xb0 = xs + ((size_t)(t0a * 128 + bb + cbv) * 128) + g4 * 8;  // step 0 base
  u16* ph = hsout + ((size_t)(t0a * 128 + bb + cbl) * 128) + un;

  // ---- prologue: x-block for steps 0..3 ----
  short8 xblk[4];
  {
    const u16* p = xb0 + (long)so * step1;
#pragma unroll
    for (int ks = 0; ks < 4; ks++) xblk[ks] = *(const short8*)(p + ks * 32);
  }
#pragma unroll
  for (int n = 0; n < 4; n++) {
    f32x4 xacc = bias4[n];
    xacc = __builtin_amdgcn_mfma_f32_16x16x32_bf16(wf[n * 8 + 0], xblk[0], xacc, 0, 0, 0);
    xacc = __builtin_amdgcn_mfma_f32_16x16x32_bf16(wf[n * 8 + 1], xblk[1], xacc, 0, 0, 0);
    xacc = __builtin_amdgcn_mfma_f32_16x16x32_bf16(wf[n * 8 + 2], xblk[2], xacc, 0, 0, 0);
    xacc = __builtin_amdgcn_mfma_f32_16x16x32_bf16(wf[n * 8 + 3], xblk[3], xacc, 0, 0, 0);
    *(f32x4*)((char*)&xstage[cb][0] + xcol + n * 64) = xacc;
  }
  {
    const u16* p = xb0 + (long)(4 + so) * step1;   // reload for block of steps 4..7
#pragma unroll
    for (int ks = 0; ks < 4; ks++) xblk[ks] = *(const short8*)(p + ks * 32);
  }
  asm volatile("s_waitcnt lgkmcnt(0)" ::: "memory");
  __builtin_amdgcn_s_barrier();
  asm volatile("" ::: "memory");

  for (int t = 0; t < T_LEN; t++) {
    int CUR = t & 1, NXT = CUR ^ 1;
    // ---- phase 1: h-MFMAs, acc-init from xstage ----
    const char* hrow = (const char*)&hbuf[CUR][0][0];
    short8 hf0 = *(const short8*)(hrow + roff[0]);
    short8 hf1 = *(const short8*)(hrow + roff[1]);
    short8 hf2 = *(const short8*)(hrow + roff[2]);
    short8 hf3 = *(const short8*)(hrow + roff[3]);
    const char* xrow = (const char*)&xstage[(t & 3) * 4 + cbv][0] + xcol;
#pragma unroll
    for (int n = 0; n < 4; n++) {
      f32x4 acc = *(const f32x4*)(xrow + n * 64);
      acc = __builtin_amdgcn_mfma_f32_16x16x32_bf16(wf[n * 8 + 4], hf0, acc, 0, 0, 0);
      acc = __builtin_amdgcn_mfma_f32_16x16x32_bf16(wf[n * 8 + 5], hf1, acc, 0, 0, 0);
      acc = __builtin_amdgcn_mfma_f32_16x16x32_bf16(wf[n * 8 + 6], hf2, acc, 0, 0, 0);
      acc = __builtin_amdgcn_mfma_f32_16x16x32_bf16(wf[n * 8 + 7], hf3, acc, 0, 0, 0);
      if (cb < 4) *(f32x4*)&zbuf[cb][zoff + n * 16] = acc;
    }
    asm volatile("s_waitcnt lgkmcnt(0)" ::: "memory");
    __builtin_amdgcn_s_barrier();
    asm volatile("" ::: "memory");
    // ---- phase 2: activation (1 chain/thread) + h writes + periodic x-block ----
    f32x4 z = *(const f32x4*)&zbuf[cbl][p0];
    float A2 = ex2(-z[0]);                 // e^-zi
    float B2 = ex2(z[1]);                  // e^{2zj}
    float F2 = ex2(-z[2]);                 // e^-(zf+1)
    float O2 = ex2(-z[3]);                 // e^-zo
    float r1 = rcp_f((1.f + A2) * (1.f + B2));
    float rf = rcp_f(1.f + F2);
    float cn = fmaf(c, rf, (B2 - 1.f) * r1);
    c = cn;
    float C2 = ex2(cn * TL2E);             // e^{2c}
    float r2 = rcp_f((1.f + C2) * (1.f + O2));
    float hv = (C2 - 1.f) * r2;            // tanh(c)*sig(zo)
    u16 hb16 = f2bf(hv);
    hbuf[NXT][cbl][un] = hb16;
    *ph = hb16;
    ph += step1;
    if ((t & 3) == 3 && t < 508) {
      // x-block for steps t+1 .. t+4 (consumes xblk = x(t+1+so))
#pragma unroll
      for (int n = 0; n < 4; n++) {
        f32x4 xacc = bias4[n];
        xacc = __builtin_amdgcn_mfma_f32_16x16x32_bf16(wf[n * 8 + 0], xblk[0], xacc, 0, 0, 0);
        xacc = __builtin_amdgcn_mfma_f32_16x16x32_bf16(wf[n * 8 + 1], xblk[1], xacc, 0, 0, 0);
        xacc = __builtin_amdgcn_mfma_f32_16x16x32_bf16(wf[n * 8 + 2], xblk[2], xacc, 0, 0, 0);
        xacc = __builtin_amdgcn_mfma_f32_16x16x32_bf16(wf[n * 8 + 3], xblk[3], xacc, 0, 0, 0);
        *(f32x4*)((char*)&xstage[cb][0] + xcol + n * 64) = xacc;
      }
      int ts = t + 5 + so;                 // next block's step for this lane
      if (ts > 511) ts = 511;              // clamp: in-bounds, value unused
      const u16* p = xb0 + (long)ts * step1;
#pragma unroll
      for (int ks = 0; ks < 4; ks++) xblk[ks] = *(const short8*)(p + ks * 32);
    }
    asm volatile("s_waitcnt lgkmcnt(0)" ::: "memory");
    __builtin_amdgcn_s_barrier();
    asm volatile("" ::: "memory");
  }
}

// ---------------- attention + FC + argmax, single pass over hs ----------------------
__global__ __launch_bounds__(512) void k_attn(const u16* __restrict__ hsf,
                                              const u16* __restrict__ hsb,
                                              const float* __restrict__ att_w,
                                              const float* __restrict__ fc_w,
                                              const float* __restrict__ fc_b,
                                              float* __restrict__ out) {
  __shared__ float rsum[8][128];
  __shared__ float esums[8];
  __shared__ float hstar[128];
  __shared__ float lg[NCLS];
  int tid = threadIdx.x, b = blockIdx.x;
  int w = tid >> 6, l = tid & 63;
  float2 aw = *(const float2*)(att_w + 2 * l);
  float r0 = 0.f, r1 = 0.f, es = 0.f;
  for (int t = w; t < T_LEN; t += 8) {
    size_t o = ((size_t)t * 128 + b) * 128 + 2 * l;
    u32 vf = *(const u32*)(hsf + o);
    u32 vb = *(const u32*)(hsb + o);
    float h0 = bf2f((u16)vf) + bf2f((u16)vb);
    float h1 = bf2f((u16)(vf >> 16)) + bf2f((u16)(vb >> 16));
    float e0 = ex2(h0 * TL2E);
    float th0 = (e0 - 1.f) * rcp_f(e0 + 1.f);
    float e1 = ex2(h1 * TL2E);
    float th1 = (e1 - 1.f) * rcp_f(e1 + 1.f);
    float s = fmaf(th0, aw.x, th1 * aw.y);
#pragma unroll
    for (int o2 = 32; o2 >= 1; o2 >>= 1) s += __shfl_xor(s, o2, 64);
    float e = ex2(s * L2E);      // no max-subtraction: |s| bounded, e^s safe in f32
    r0 = fmaf(e, h0, r0); r1 = fmaf(e, h1, r1); es += e;
  }
  rsum[w][2 * l] = r0;
  rsum[w][2 * l + 1] = r1;
  if (l == 0) esums[w] = es;
  __syncthreads();
  if (tid < 128) {
    float r = 0.f, et = 0.f;
#pragma unroll
    for (int i = 0; i < 8; i++) { r += rsum[i][tid]; et += esums[i]; }
    float rr = r / et;
    float e2 = ex2(rr * TL2E);
    hstar[tid] = (e2 - 1.f) * rcp_f(e2 + 1.f);
  }
  __syncthreads();
  if (tid < NCLS) {
    float acc = fc_b[tid];
#pragma unroll 4
    for (int hh = 0; hh < 128; hh++) acc = fmaf(hstar[hh], fc_w[hh * NCLS + tid], acc);
    out[b * NCLS + tid] = acc;
    lg[tid] = acc;
  }
  __syncthreads();
  if (tid == 0) {
    int best = 0; float bv = lg[0];
    for (int l2 = 1; l2 < NCLS; l2++)
      if (lg[l2] > bv) { bv = lg[l2]; best = l2; }
    out[2432 + b] = (float)best;   // predict_label_ids
    out[2561 + b] = (float)best;   // probabilities (argmax of softmax == argmax)
  }
}

// ---------------- l2 loss ----------------------------------------------------------
__global__ __launch_bounds__(256) void k_l2(const float* __restrict__ fc_w,
                                            const float* __restrict__ fc_b,
                                            float* __restrict__ out) {
  __shared__ float red[256];
  int tid = threadIdx.x;
  float a = 0.f;
  for (int i = tid; i < 128 * NCLS; i += 256) a += fc_w[i] * fc_w[i];
  if (tid < NCLS) a += fc_b[tid] * fc_b[tid];
  red[tid] = a; __syncthreads();
  for (int s = 128; s >= 1; s >>= 1) {
    if (tid < s) red[tid] += red[tid + s];
    __syncthreads();
  }
  if (tid == 0) out[2560] = 0.5f * red[0];
}

extern "C" void kernel_launch(void* const* d_in, const int* in_sizes, int n_in,
                              void* d_out, int out_size, void* d_ws, size_t ws_size,
                              hipStream_t stream) {
  const int* ids = (const int*)d_in[0];
  const float* table = (const float*)d_in[1];
  const float* fw_k = (const float*)d_in[2];
  const float* fw_b = (const float*)d_in[3];
  const float* bw_k = (const float*)d_in[4];
  const float* bw_b = (const float*)d_in[5];
  const float* att_w = (const float*)d_in[6];
  const float* fc_w = (const float*)d_in[7];
  const float* fc_b = (const float*)d_in[8];
  float* out = (float*)d_out;
  char* ws = (char*)d_ws;

  u16* xs = (u16*)(ws + 0);                    // 16,777,216 B   xs[t*128+b][128] bf16
  u16* wt_bf = (u16*)(ws + 16777216);          //    524,288 B   [2][512][256] bf16
  float* bias_pre = (float*)(ws + 17301504);   //      4,096 B
  u16* hs_fw = (u16*)(ws + 17305600);          // 16,777,216 B   [t][b][u] bf16
  u16* hs_bw = (u16*)(ws + 34082816);          // 16,777,216 B   (end 50,860,032)

  hipLaunchKernelGGL(k_embed, dim3(8192), dim3(256), 0, stream, ids, table, xs);
  hipLaunchKernelGGL(k_prep, dim3(1025), dim3(256), 0, stream, fw_k, bw_k, fw_b, bw_b,
                     wt_bf, bias_pre);
  hipLaunchKernelGGL(k_lstm, dim3(64), dim3(512), 0, stream, wt_bf, bias_pre, xs,
                     hs_fw, hs_bw);
  hipLaunchKernelGGL(k_attn, dim3(128), dim3(512), 0, stream, hs_fw, hs_bw, att_w,
                     fc_w, fc_b, out);
  hipLaunchKernelGGL(k_l2, dim3(1), dim3(256), 0, stream, fc_w, fc_b, out);
}

// Round 14
// 438.486 us; speedup vs baseline: 1.9651x; 1.0730x over previous
//
#include <hip/hip_runtime.h>

typedef unsigned short u16;
typedef unsigned int u32;
typedef short short8 __attribute__((ext_vector_type(8)));
typedef float f32x4 __attribute__((ext_vector_type(4)));

#define T_LEN 512
#define NCLS 19

#define L2E 1.4426950408889634f
#define TL2E 2.8853901617765067f

static __device__ __forceinline__ u16 f2bf(float f) {
  u32 u = __float_as_uint(f);
  u32 r = (u + 0x7FFFu + ((u >> 16) & 1u)) >> 16;
  return (u16)r;
}
static __device__ __forceinline__ float bf2f(u16 h) {
  return __uint_as_float(((u32)h) << 16);
}
static __device__ __forceinline__ float rcp_f(float x) { return __builtin_amdgcn_rcpf(x); }
static __device__ __forceinline__ float ex2(float x) { return __builtin_amdgcn_exp2f(x); }

// ---------------- embedding gather + cast to bf16, layout xs[t*B+b][d] -------------
__global__ __launch_bounds__(256) void k_embed(const int* __restrict__ ids,
                                               const float* __restrict__ table,
                                               u16* __restrict__ xs) {
  int i = blockIdx.x * 256 + threadIdx.x;
  int e = i * 4;               // element index, total T*B*D = 8388608
  int m = e >> 7;              // row = t*B + b
  int col = e & 127;
  int t = m >> 7, b = m & 127;
  int id = ids[b * T_LEN + t];
  float4 v = *(const float4*)(table + (size_t)id * 128 + col);
  ushort4 o;
  o.x = f2bf(v.x); o.y = f2bf(v.y); o.z = f2bf(v.z); o.w = f2bf(v.w);
  *(ushort4*)(xs + (size_t)m * 128 + col) = o;
}

// ---------------- weight prep (r5/r9/r11-proven, UNCHANGED) ------------------------
// p = w*64 + nt*16 + g4*4 + q  <->  unit u = w*16 + g4*4 + nt, gate q; col j = q*128+u.
// Weights pre-scaled by log2e (2*log2e for q==1); bias includes forget +1, scaled.
__global__ __launch_bounds__(256) void k_prep(const float* __restrict__ fw_k,
                                              const float* __restrict__ bw_k,
                                              const float* __restrict__ fw_b,
                                              const float* __restrict__ bw_b,
                                              u16* __restrict__ wt_bf,
                                              float* __restrict__ bias_pre) {
  int wg = blockIdx.x;
  int tid = threadIdx.x;
  if (wg < 1024) {
    int i = wg * 256 + tid;
    int n = i >> 8, k = i & 255;
    int dir = n >> 9, p = n & 511;
    int w = p >> 6, nt = (p >> 4) & 3, g4 = (p >> 2) & 3, q = p & 3;
    int u = w * 16 + g4 * 4 + nt;
    int j = q * 128 + u;
    float sc = (q == 1) ? TL2E : L2E;
    const float* K = dir ? bw_k : fw_k;
    wt_bf[i] = f2bf(K[k * 512 + j] * sc);
  } else {
    for (int uu = 0; uu < 4; uu++) {
      int n = uu * 256 + tid;
      int dir = n >> 9, p = n & 511;
      int w = p >> 6, nt = (p >> 4) & 3, g4 = (p >> 2) & 3, q = p & 3;
      int u = w * 16 + g4 * 4 + nt;
      int j = q * 128 + u;
      float sc = (q == 1) ? TL2E : L2E;
      float bv = (dir ? bw_b : fw_b)[j] + (q == 2 ? 1.0f : 0.0f);
      bias_pre[n] = bv * sc;
    }
  }
}

// ---------------- fused LSTM: 64 WGs, 4-step-batched x-projection ------------------
// r12 structure/schedule (passing). Single delta: phase-1 MFMA accs init to 0; the
// x-projection z_x (incl. bias, fp32) is ADDED by the activation thread in phase 2 —
// removes 32 ds_read_b128/step from phase 1 (the LDS-pipe wall). The x-block rewrite
// in phase 2 is preceded by an EXTRA BARRIER so no thread's z_x read can race with
// the overwrite (the r13 NaN). All z traffic stays fp32 (no precision change).
__global__ __launch_bounds__(512, 2) void k_lstm(const u16* __restrict__ wt_bf,
                                                 const float* __restrict__ bias_pre,
                                                 const u16* __restrict__ xs,
                                                 u16* __restrict__ hs_fw,
                                                 u16* __restrict__ hs_bw) {
  __shared__ u16 hbuf[2][4][144];     // double-buffered h, 288B rows (padded, r11)
  __shared__ float zbuf[4][520];      // z_h exchange, padded rows (r11)
  __shared__ float xstage[16][520];   // z_x for 4 steps: row = so*4+cbv, col = gate p
  int tid = threadIdx.x;
  int wg = blockIdx.x;
  int dir = wg >> 5;
  int bb = (wg & 31) * 4;             // batch base (4 per WG)
  int w = tid >> 6, l = tid & 63;
  int cb = l & 15, g4 = l >> 4;
  int cbv = cb & 3;                   // batch index within group
  int so = cb >> 2;                   // step-offset role of this lane in the x-block

  // resident A-frags: W^T full K=256 (128 regs -> AGPRs), r9/r11-verbatim indices
  short8 wf[32];
#pragma unroll
  for (int n = 0; n < 4; n++) {
    const u16* wb = wt_bf + ((size_t)(dir * 512 + w * 64 + n * 16 + cb) * 256) + g4 * 8;
#pragma unroll
    for (int ks = 0; ks < 8; ks++)
      wf[n * 8 + ks] = *(const short8*)(wb + ks * 32);
  }
  f32x4 bias4[4];
#pragma unroll
  for (int n = 0; n < 4; n++)
    bias4[n] = *(const f32x4*)(bias_pre + dir * 512 + w * 64 + n * 16 + g4 * 4);

  // activation ownership: thread -> (batch cbl, unit un)   (r11-verbatim)
  int cbl = tid >> 7;                 // 0..3
  int un = tid & 127;                 // unit
  int p0 = (un >> 4) * 64 + (un & 3) * 16 + ((un >> 2) & 3) * 4;
  float c = 0.0f;

  int roff[4];
#pragma unroll
  for (int ks = 0; ks < 4; ks++)
    roff[ks] = cbv * 288 + ks * 64 + g4 * 16;   // bytes into a hbuf slot (row=288B)
  int zoff = w * 64 + g4 * 4;                   // + n*16 at write time (floats)
  int xcol = w * 256 + g4 * 16;                 // byte offset within an xstage row: + n*64

  // zero both h buffers (h(0)=0): 2*4*144 u16 = 576 u32
  u32* hz = (u32*)hbuf;
  hz[tid >= 512 ? 0 : tid] = 0;
  if (tid < 64) hz[512 + tid] = 0;
  __syncthreads();

  int t0a = dir ? (T_LEN - 1) : 0;
  int stp = dir ? -1 : 1;
  u16* hsout = dir ? hs_bw : hs_fw;
  long step1 = (long)stp * 16384;     // one time step, elements

  const u16* xb0 = xs + ((size_t)(t0a * 128 + bb + cbv) * 128) + g4 * 8;  // step 0 base
  u16* ph = hsout + ((size_t)(t0a * 128 + bb + cbl) * 128) + un;

  // ---- prologue: x-block (z_x incl. bias) for steps 0..3 ----
  short8 xblk[4];
  {
    const u16* p = xb0 + (long)so * step1;
#pragma unroll
    for (int ks = 0; ks < 4; ks++) xblk[ks] = *(const short8*)(p + ks * 32);
  }
#pragma unroll
  for (int n = 0; n < 4; n++) {
    f32x4 xacc = bias4[n];
    xacc = __builtin_amdgcn_mfma_f32_16x16x32_bf16(wf[n * 8 + 0], xblk[0], xacc, 0, 0, 0);
    xacc = __builtin_amdgcn_mfma_f32_16x16x32_bf16(wf[n * 8 + 1], xblk[1], xacc, 0, 0, 0);
    xacc = __builtin_amdgcn_mfma_f32_16x16x32_bf16(wf[n * 8 + 2], xblk[2], xacc, 0, 0, 0);
    xacc = __builtin_amdgcn_mfma_f32_16x16x32_bf16(wf[n * 8 + 3], xblk[3], xacc, 0, 0, 0);
    *(f32x4*)((char*)&xstage[cb][0] + xcol + n * 64) = xacc;
  }
  {
    const u16* p = xb0 + (long)(4 + so) * step1;   // reload for block of steps 4..7
#pragma unroll
    for (int ks = 0; ks < 4; ks++) xblk[ks] = *(const short8*)(p + ks * 32);
  }
  asm volatile("s_waitcnt lgkmcnt(0)" ::: "memory");
  __builtin_amdgcn_s_barrier();
  asm volatile("" ::: "memory");

  for (int t = 0; t < T_LEN; t++) {
    int CUR = t & 1, NXT = CUR ^ 1;
    // ---- phase 1: h-MFMAs only (acc init 0), z_h -> zbuf ----
    const char* hrow = (const char*)&hbuf[CUR][0][0];
    short8 hf0 = *(const short8*)(hrow + roff[0]);
    short8 hf1 = *(const short8*)(hrow + roff[1]);
    short8 hf2 = *(const short8*)(hrow + roff[2]);
    short8 hf3 = *(const short8*)(hrow + roff[3]);
#pragma unroll
    for (int n = 0; n < 4; n++) {
      f32x4 acc = {0.f, 0.f, 0.f, 0.f};
      acc = __builtin_amdgcn_mfma_f32_16x16x32_bf16(wf[n * 8 + 4], hf0, acc, 0, 0, 0);
      acc = __builtin_amdgcn_mfma_f32_16x16x32_bf16(wf[n * 8 + 5], hf1, acc, 0, 0, 0);
      acc = __builtin_amdgcn_mfma_f32_16x16x32_bf16(wf[n * 8 + 6], hf2, acc, 0, 0, 0);
      acc = __builtin_amdgcn_mfma_f32_16x16x32_bf16(wf[n * 8 + 7], hf3, acc, 0, 0, 0);
      if (cb < 4) *(f32x4*)&zbuf[cb][zoff + n * 16] = acc;
    }
    asm volatile("s_waitcnt lgkmcnt(0)" ::: "memory");
    __builtin_amdgcn_s_barrier();
    asm volatile("" ::: "memory");
    // ---- phase 2: activation (z = z_h + z_x, fp32), h writes, periodic x-block ----
    f32x4 zh = *(const f32x4*)&zbuf[cbl][p0];
    f32x4 zx = *(const f32x4*)&xstage[(t & 3) * 4 + cbl][p0];
    float z0 = zh[0] + zx[0];
    float z1 = zh[1] + zx[1];
    float z2 = zh[2] + zx[2];
    float z3 = zh[3] + zx[3];
    float A2 = ex2(-z0);                   // e^-zi
    float B2 = ex2(z1);                    // e^{2zj}
    float F2 = ex2(-z2);                   // e^-(zf+1)
    float O2 = ex2(-z3);                   // e^-zo
    float r1 = rcp_f((1.f + A2) * (1.f + B2));
    float rf = rcp_f(1.f + F2);
    float cn = fmaf(c, rf, (B2 - 1.f) * r1);
    c = cn;
    float C2 = ex2(cn * TL2E);             // e^{2c}
    float r2 = rcp_f((1.f + C2) * (1.f + O2));
    float hv = (C2 - 1.f) * r2;            // tanh(c)*sig(zo)
    u16 hb16 = f2bf(hv);
    hbuf[NXT][cbl][un] = hb16;
    *ph = hb16;
    ph += step1;
    if ((t & 3) == 3 && t < 508) {
      // RACE FIX: all threads' z_x reads (above) must complete before the rewrite.
      asm volatile("s_waitcnt lgkmcnt(0)" ::: "memory");
      __builtin_amdgcn_s_barrier();
      asm volatile("" ::: "memory");
      // x-block for steps t+1 .. t+4 (consumes xblk = x(t+1+so))
#pragma unroll
      for (int n = 0; n < 4; n++) {
        f32x4 xacc = bias4[n];
        xacc = __builtin_amdgcn_mfma_f32_16x16x32_bf16(wf[n * 8 + 0], xblk[0], xacc, 0, 0, 0);
        xacc = __builtin_amdgcn_mfma_f32_16x16x32_bf16(wf[n * 8 + 1], xblk[1], xacc, 0, 0, 0);
        xacc = __builtin_amdgcn_mfma_f32_16x16x32_bf16(wf[n * 8 + 2], xblk[2], xacc, 0, 0, 0);
        xacc = __builtin_amdgcn_mfma_f32_16x16x32_bf16(wf[n * 8 + 3], xblk[3], xacc, 0, 0, 0);
        *(f32x4*)((char*)&xstage[cb][0] + xcol + n * 64) = xacc;
      }
      int ts = t + 5 + so;                 // next block's step for this lane
      if (ts > 511) ts = 511;              // clamp: in-bounds, value unused
      const u16* p = xb0 + (long)ts * step1;
#pragma unroll
      for (int ks = 0; ks < 4; ks++) xblk[ks] = *(const short8*)(p + ks * 32);
    }
    asm volatile("s_waitcnt lgkmcnt(0)" ::: "memory");
    __builtin_amdgcn_s_barrier();
    asm volatile("" ::: "memory");
  }
}

// ---------------- attention + FC + argmax, single pass over hs ----------------------
__global__ __launch_bounds__(512) void k_attn(const u16* __restrict__ hsf,
                                              const u16* __restrict__ hsb,
                                              const float* __restrict__ att_w,
                                              const float* __restrict__ fc_w,
                                              const float* __restrict__ fc_b,
                                              float* __restrict__ out) {
  __shared__ float rsum[8][128];
  __shared__ float esums[8];
  __shared__ float hstar[128];
  __shared__ float lg[NCLS];
  int tid = threadIdx.x, b = blockIdx.x;
  int w = tid >> 6, l = tid & 63;
  float2 aw = *(const float2*)(att_w + 2 * l);
  float r0 = 0.f, r1 = 0.f, es = 0.f;
  for (int t = w; t < T_LEN; t += 8) {
    size_t o = ((size_t)t * 128 + b) * 128 + 2 * l;
    u32 vf = *(const u32*)(hsf + o);
    u32 vb = *(const u32*)(hsb + o);
    float h0 = bf2f((u16)vf) + bf2f((u16)vb);
    float h1 = bf2f((u16)(vf >> 16)) + bf2f((u16)(vb >> 16));
    float e0 = ex2(h0 * TL2E);
    float th0 = (e0 - 1.f) * rcp_f(e0 + 1.f);
    float e1 = ex2(h1 * TL2E);
    float th1 = (e1 - 1.f) * rcp_f(e1 + 1.f);
    float s = fmaf(th0, aw.x, th1 * aw.y);
#pragma unroll
    for (int o2 = 32; o2 >= 1; o2 >>= 1) s += __shfl_xor(s, o2, 64);
    float e = ex2(s * L2E);      // no max-subtraction: |s| bounded, e^s safe in f32
    r0 = fmaf(e, h0, r0); r1 = fmaf(e, h1, r1); es += e;
  }
  rsum[w][2 * l] = r0;
  rsum[w][2 * l + 1] = r1;
  if (l == 0) esums[w] = es;
  __syncthreads();
  if (tid < 128) {
    float r = 0.f, et = 0.f;
#pragma unroll
    for (int i = 0; i < 8; i++) { r += rsum[i][tid]; et += esums[i]; }
    float rr = r / et;
    float e2 = ex2(rr * TL2E);
    hstar[tid] = (e2 - 1.f) * rcp_f(e2 + 1.f);
  }
  __syncthreads();
  if (tid < NCLS) {
    float acc = fc_b[tid];
#pragma unroll 4
    for (int hh = 0; hh < 128; hh++) acc = fmaf(hstar[hh], fc_w[hh * NCLS + tid], acc);
    out[b * NCLS + tid] = acc;
    lg[tid] = acc;
  }
  __syncthreads();
  if (tid == 0) {
    int best = 0; float bv = lg[0];
    for (int l2 = 1; l2 < NCLS; l2++)
      if (lg[l2] > bv) { bv = lg[l2]; best = l2; }
    out[2432 + b] = (float)best;   // predict_label_ids
    out[2561 + b] = (float)best;   // probabilities (argmax of softmax == argmax)
  }
}

// ---------------- l2 loss ----------------------------------------------------------
__global__ __launch_bounds__(256) void k_l2(const float* __restrict__ fc_w,
                                            const float* __restrict__ fc_b,
                                            float* __restrict__ out) {
  __shared__ float red[256];
  int tid = threadIdx.x;
  float a = 0.f;
  for (int i = tid; i < 128 * NCLS; i += 256) a += fc_w[i] * fc_w[i];
  if (tid < NCLS) a += fc_b[tid] * fc_b[tid];
  red[tid] = a; __syncthreads();
  for (int s = 128; s >= 1; s >>= 1) {
    if (tid < s) red[tid] += red[tid + s];
    __syncthreads();
  }
  if (tid == 0) out[2560] = 0.5f * red[0];
}

extern "C" void kernel_launch(void* const* d_in, const int* in_sizes, int n_in,
                              void* d_out, int out_size, void* d_ws, size_t ws_size,
                              hipStream_t stream) {
  const int* ids = (const int*)d_in[0];
  const float* table = (const float*)d_in[1];
  const float* fw_k = (const float*)d_in[2];
  const float* fw_b = (const float*)d_in[3];
  const float* bw_k = (const float*)d_in[4];
  const float* bw_b = (const float*)d_in[5];
  const float* att_w = (const float*)d_in[6];
  const float* fc_w = (const float*)d_in[7];
  const float* fc_b = (const float*)d_in[8];
  float* out = (float*)d_out;
  char* ws = (char*)d_ws;

  u16* xs = (u16*)(ws + 0);                    // 16,777,216 B   xs[t*128+b][128] bf16
  u16* wt_bf = (u16*)(ws + 16777216);          //    524,288 B   [2][512][256] bf16
  float* bias_pre = (float*)(ws + 17301504);   //      4,096 B
  u16* hs_fw = (u16*)(ws + 17305600);          // 16,777,216 B   [t][b][u] bf16
  u16* hs_bw = (u16*)(ws + 34082816);          // 16,777,216 B   (end 50,860,032)

  hipLaunchKernelGGL(k_embed, dim3(8192), dim3(256), 0, stream, ids, table, xs);
  hipLaunchKernelGGL(k_prep, dim3(1025), dim3(256), 0, stream, fw_k, bw_k, fw_b, bw_b,
                     wt_bf, bias_pre);
  hipLaunchKernelGGL(k_lstm, dim3(64), dim3(512), 0, stream, wt_bf, bias_pre, xs,
                     hs_fw, hs_bw);
  hipLaunchKernelGGL(k_attn, dim3(128), dim3(512), 0, stream, hs_fw, hs_bw, att_w,
                     fc_w, fc_b, out);
  hipLaunchKernelGGL(k_l2, dim3(1), dim3(256), 0, stream, fc_w, fc_b, out);
}

// Round 15
// 356.490 us; speedup vs baseline: 2.4171x; 1.2300x over previous
//
#include <hip/hip_runtime.h>

typedef unsigned short u16;
typedef unsigned int u32;
typedef short short8 __attribute__((ext_vector_type(8)));
typedef float f32x4 __attribute__((ext_vector_type(4)));

#define T_LEN 512
#define NCLS 19

#define L2E 1.4426950408889634f
#define TL2E 2.8853901617765067f

static __device__ __forceinline__ u16 f2bf(float f) {
  u32 u = __float_as_uint(f);
  u32 r = (u + 0x7FFFu + ((u >> 16) & 1u)) >> 16;
  return (u16)r;
}
static __device__ __forceinline__ float bf2f(u16 h) {
  return __uint_as_float(((u32)h) << 16);
}
static __device__ __forceinline__ float rcp_f(float x) { return __builtin_amdgcn_rcpf(x); }
static __device__ __forceinline__ float ex2(float x) { return __builtin_amdgcn_exp2f(x); }

// ---------------- embedding gather + cast to bf16, layout xs[t*B+b][d] -------------
__global__ __launch_bounds__(256) void k_embed(const int* __restrict__ ids,
                                               const float* __restrict__ table,
                                               u16* __restrict__ xs) {
  int i = blockIdx.x * 256 + threadIdx.x;
  int e = i * 4;               // element index, total T*B*D = 8388608
  int m = e >> 7;              // row = t*B + b
  int col = e & 127;
  int t = m >> 7, b = m & 127;
  int id = ids[b * T_LEN + t];
  float4 v = *(const float4*)(table + (size_t)id * 128 + col);
  ushort4 o;
  o.x = f2bf(v.x); o.y = f2bf(v.y); o.z = f2bf(v.z); o.w = f2bf(v.w);
  *(ushort4*)(xs + (size_t)m * 128 + col) = o;
}

// ---------------- weight prep (r5/r9/r11-proven, UNCHANGED) ------------------------
// p = w*64 + nt*16 + g4*4 + q  <->  unit u = w*16 + g4*4 + nt, gate q; col j = q*128+u.
// Weights pre-scaled by log2e (2*log2e for q==1); bias includes forget +1, scaled.
__global__ __launch_bounds__(256) void k_prep(const float* __restrict__ fw_k,
                                              const float* __restrict__ bw_k,
                                              const float* __restrict__ fw_b,
                                              const float* __restrict__ bw_b,
                                              u16* __restrict__ wt_bf,
                                              float* __restrict__ bias_pre) {
  int wg = blockIdx.x;
  int tid = threadIdx.x;
  if (wg < 1024) {
    int i = wg * 256 + tid;
    int n = i >> 8, k = i & 255;
    int dir = n >> 9, p = n & 511;
    int w = p >> 6, nt = (p >> 4) & 3, g4 = (p >> 2) & 3, q = p & 3;
    int u = w * 16 + g4 * 4 + nt;
    int j = q * 128 + u;
    float sc = (q == 1) ? TL2E : L2E;
    const float* K = dir ? bw_k : fw_k;
    wt_bf[i] = f2bf(K[k * 512 + j] * sc);
  } else {
    for (int uu = 0; uu < 4; uu++) {
      int n = uu * 256 + tid;
      int dir = n >> 9, p = n & 511;
      int w = p >> 6, nt = (p >> 4) & 3, g4 = (p >> 2) & 3, q = p & 3;
      int u = w * 16 + g4 * 4 + nt;
      int j = q * 128 + u;
      float sc = (q == 1) ? TL2E : L2E;
      float bv = (dir ? bw_b : fw_b)[j] + (q == 2 ? 1.0f : 0.0f);
      bias_pre[n] = bv * sc;
    }
  }
}

// ---------------- fused LSTM: 64 WGs, in-accumulator activation --------------------
// r14 frame (64 WGs, 4-step x-block, padded hbuf). Key change: NO zbuf. The 4x
// duplicated MFMA columns make every lane's acc valid, so lane (cb=4*so+cbv, g4)
// activates tile n=so from its OWN accumulator (cndmask select, no runtime index),
// covering all (batch,unit) pairs bijectively with ONE chain per lane. z_x is read
// r14-style (1 b128/thread) and added in fp32. ONE barrier/step (2 on x-block steps).
__global__ __launch_bounds__(512, 2) void k_lstm(const u16* __restrict__ wt_bf,
                                                 const float* __restrict__ bias_pre,
                                                 const u16* __restrict__ xs,
                                                 u16* __restrict__ hs_fw,
                                                 u16* __restrict__ hs_bw) {
  __shared__ u16 hbuf[2][4][144];     // double-buffered h, 288B rows (padded, r11)
  __shared__ float xstage[16][524];   // z_x for 4 steps: row = so*4+cbv, col = gate p
  int tid = threadIdx.x;
  int wg = blockIdx.x;
  int dir = wg >> 5;
  int bb = (wg & 31) * 4;             // batch base (4 per WG)
  int w = tid >> 6, l = tid & 63;
  int cb = l & 15, g4 = l >> 4;
  int cbv = cb & 3;                   // batch index within group
  int so = cb >> 2;                   // this lane's tile/step-offset role

  // resident A-frags: W^T full K=256 (128 regs -> AGPRs), r9/r11-verbatim indices
  short8 wf[32];
#pragma unroll
  for (int n = 0; n < 4; n++) {
    const u16* wb = wt_bf + ((size_t)(dir * 512 + w * 64 + n * 16 + cb) * 256) + g4 * 8;
#pragma unroll
    for (int ks = 0; ks < 8; ks++)
      wf[n * 8 + ks] = *(const short8*)(wb + ks * 32);
  }
  f32x4 bias4[4];
#pragma unroll
  for (int n = 0; n < 4; n++)
    bias4[n] = *(const f32x4*)(bias_pre + dir * 512 + w * 64 + n * 16 + g4 * 4);

  float c = 0.0f;                     // cell state for (batch cbv, unit u_so)
  int u_so = w * 16 + g4 * 4 + so;

  int roff[4];
#pragma unroll
  for (int ks = 0; ks < 4; ks++)
    roff[ks] = cbv * 288 + ks * 64 + g4 * 16;   // bytes into a hbuf slot (row=288B)
  int xcol = w * 256 + g4 * 16;                 // byte offset within an xstage row: + n*64

  // zero both h buffers (h(0)=0): 2*4*144 u16 = 576 u32
  u32* hz = (u32*)hbuf;
  hz[tid >= 512 ? 0 : tid] = 0;
  if (tid < 64) hz[512 + tid] = 0;
  __syncthreads();

  int t0a = dir ? (T_LEN - 1) : 0;
  int stp = dir ? -1 : 1;
  u16* hsout = dir ? hs_bw : hs_fw;
  long step1 = (long)stp * 16384;     // one time step, elements

  const u16* xb0 = xs + ((size_t)(t0a * 128 + bb + cbv) * 128) + g4 * 8;  // step 0 base
  u16* ph = hsout + ((size_t)(t0a * 128 + bb + cbv) * 128) + u_so;

  // ---- prologue: x-block (z_x incl. bias) for steps 0..3 ----
  short8 xblk[4];
  {
    const u16* p = xb0 + (long)so * step1;
#pragma unroll
    for (int ks = 0; ks < 4; ks++) xblk[ks] = *(const short8*)(p + ks * 32);
  }
#pragma unroll
  for (int n = 0; n < 4; n++) {
    f32x4 xacc = bias4[n];
    xacc = __builtin_amdgcn_mfma_f32_16x16x32_bf16(wf[n * 8 + 0], xblk[0], xacc, 0, 0, 0);
    xacc = __builtin_amdgcn_mfma_f32_16x16x32_bf16(wf[n * 8 + 1], xblk[1], xacc, 0, 0, 0);
    xacc = __builtin_amdgcn_mfma_f32_16x16x32_bf16(wf[n * 8 + 2], xblk[2], xacc, 0, 0, 0);
    xacc = __builtin_amdgcn_mfma_f32_16x16x32_bf16(wf[n * 8 + 3], xblk[3], xacc, 0, 0, 0);
    *(f32x4*)((char*)&xstage[cb][0] + xcol + n * 64) = xacc;
  }
  {
    const u16* p = xb0 + (long)(4 + so) * step1;   // reload for block of steps 4..7
#pragma unroll
    for (int ks = 0; ks < 4; ks++) xblk[ks] = *(const short8*)(p + ks * 32);
  }
  asm volatile("s_waitcnt lgkmcnt(0)" ::: "memory");
  __builtin_amdgcn_s_barrier();
  asm volatile("" ::: "memory");

  for (int t = 0; t < T_LEN; t++) {
    int CUR = t & 1, NXT = CUR ^ 1;
    // ---- h-MFMAs (acc init 0), all in registers ----
    const char* hrow = (const char*)&hbuf[CUR][0][0];
    short8 hf0 = *(const short8*)(hrow + roff[0]);
    short8 hf1 = *(const short8*)(hrow + roff[1]);
    short8 hf2 = *(const short8*)(hrow + roff[2]);
    short8 hf3 = *(const short8*)(hrow + roff[3]);
    f32x4 a0 = {0.f, 0.f, 0.f, 0.f}, a1 = a0, a2 = a0, a3 = a0;
    a0 = __builtin_amdgcn_mfma_f32_16x16x32_bf16(wf[4],  hf0, a0, 0, 0, 0);
    a1 = __builtin_amdgcn_mfma_f32_16x16x32_bf16(wf[12], hf0, a1, 0, 0, 0);
    a2 = __builtin_amdgcn_mfma_f32_16x16x32_bf16(wf[20], hf0, a2, 0, 0, 0);
    a3 = __builtin_amdgcn_mfma_f32_16x16x32_bf16(wf[28], hf0, a3, 0, 0, 0);
    a0 = __builtin_amdgcn_mfma_f32_16x16x32_bf16(wf[5],  hf1, a0, 0, 0, 0);
    a1 = __builtin_amdgcn_mfma_f32_16x16x32_bf16(wf[13], hf1, a1, 0, 0, 0);
    a2 = __builtin_amdgcn_mfma_f32_16x16x32_bf16(wf[21], hf1, a2, 0, 0, 0);
    a3 = __builtin_amdgcn_mfma_f32_16x16x32_bf16(wf[29], hf1, a3, 0, 0, 0);
    a0 = __builtin_amdgcn_mfma_f32_16x16x32_bf16(wf[6],  hf2, a0, 0, 0, 0);
    a1 = __builtin_amdgcn_mfma_f32_16x16x32_bf16(wf[14], hf2, a1, 0, 0, 0);
    a2 = __builtin_amdgcn_mfma_f32_16x16x32_bf16(wf[22], hf2, a2, 0, 0, 0);
    a3 = __builtin_amdgcn_mfma_f32_16x16x32_bf16(wf[30], hf2, a3, 0, 0, 0);
    a0 = __builtin_amdgcn_mfma_f32_16x16x32_bf16(wf[7],  hf3, a0, 0, 0, 0);
    a1 = __builtin_amdgcn_mfma_f32_16x16x32_bf16(wf[15], hf3, a1, 0, 0, 0);
    a2 = __builtin_amdgcn_mfma_f32_16x16x32_bf16(wf[23], hf3, a2, 0, 0, 0);
    a3 = __builtin_amdgcn_mfma_f32_16x16x32_bf16(wf[31], hf3, a3, 0, 0, 0);
    // ---- select own tile (lane-varying cndmask, no runtime indexing) ----
    f32x4 zA = (so & 2) ? a2 : a0;
    f32x4 zB = (so & 2) ? a3 : a1;
    f32x4 zh = (so & 1) ? zB : zA;
    f32x4 zx = *(const f32x4*)&xstage[(t & 3) * 4 + cbv][w * 64 + so * 16 + g4 * 4];
    float z0 = zh[0] + zx[0];
    float z1 = zh[1] + zx[1];
    float z2 = zh[2] + zx[2];
    float z3 = zh[3] + zx[3];
    float A2 = ex2(-z0);                   // e^-zi
    float B2 = ex2(z1);                    // e^{2zj}
    float F2 = ex2(-z2);                   // e^-(zf+1)
    float O2 = ex2(-z3);                   // e^-zo
    float r1 = rcp_f((1.f + A2) * (1.f + B2));
    float rf = rcp_f(1.f + F2);
    float cn = fmaf(c, rf, (B2 - 1.f) * r1);
    c = cn;
    float C2 = ex2(cn * TL2E);             // e^{2c}
    float r2 = rcp_f((1.f + C2) * (1.f + O2));
    float hv = (C2 - 1.f) * r2;            // tanh(c)*sig(zo)
    u16 hb16 = f2bf(hv);
    hbuf[NXT][cbv][u_so] = hb16;           // all 64 lanes, bijective coverage
    *ph = hb16;
    ph += step1;
    asm volatile("s_waitcnt lgkmcnt(0)" ::: "memory");
    __builtin_amdgcn_s_barrier();
    asm volatile("" ::: "memory");
    if ((t & 3) == 3 && t < 508) {
      // x-block for steps t+1 .. t+4 (B1 above separates all xstage reads from this)
#pragma unroll
      for (int n = 0; n < 4; n++) {
        f32x4 xacc = bias4[n];
        xacc = __builtin_amdgcn_mfma_f32_16x16x32_bf16(wf[n * 8 + 0], xblk[0], xacc, 0, 0, 0);
        xacc = __builtin_amdgcn_mfma_f32_16x16x32_bf16(wf[n * 8 + 1], xblk[1], xacc, 0, 0, 0);
        xacc = __builtin_amdgcn_mfma_f32_16x16x32_bf16(wf[n * 8 + 2], xblk[2], xacc, 0, 0, 0);
        xacc = __builtin_amdgcn_mfma_f32_16x16x32_bf16(wf[n * 8 + 3], xblk[3], xacc, 0, 0, 0);
        *(f32x4*)((char*)&xstage[cb][0] + xcol + n * 64) = xacc;
      }
      int ts = t + 5 + so;                 // next block's step for this lane
      if (ts > 511) ts = 511;              // clamp: in-bounds, value unused
      const u16* p = xb0 + (long)ts * step1;
#pragma unroll
      for (int ks = 0; ks < 4; ks++) xblk[ks] = *(const short8*)(p + ks * 32);
      asm volatile("s_waitcnt lgkmcnt(0)" ::: "memory");
      __builtin_amdgcn_s_barrier();
      asm volatile("" ::: "memory");
    }
  }
}

// ---------------- attention + FC + argmax, single pass over hs ----------------------
__global__ __launch_bounds__(512) void k_attn(const u16* __restrict__ hsf,
                                              const u16* __restrict__ hsb,
                                              const float* __restrict__ att_w,
                                              const float* __restrict__ fc_w,
                                              const float* __restrict__ fc_b,
                                              float* __restrict__ out) {
  __shared__ float rsum[8][128];
  __shared__ float esums[8];
  __shared__ float hstar[128];
  __shared__ float lg[NCLS];
  int tid = threadIdx.x, b = blockIdx.x;
  int w = tid >> 6, l = tid & 63;
  float2 aw = *(const float2*)(att_w + 2 * l);
  float r0 = 0.f, r1 = 0.f, es = 0.f;
  for (int t = w; t < T_LEN; t += 8) {
    size_t o = ((size_t)t * 128 + b) * 128 + 2 * l;
    u32 vf = *(const u32*)(hsf + o);
    u32 vb = *(const u32*)(hsb + o);
    float h0 = bf2f((u16)vf) + bf2f((u16)vb);
    float h1 = bf2f((u16)(vf >> 16)) + bf2f((u16)(vb >> 16));
    float e0 = ex2(h0 * TL2E);
    float th0 = (e0 - 1.f) * rcp_f(e0 + 1.f);
    float e1 = ex2(h1 * TL2E);
    float th1 = (e1 - 1.f) * rcp_f(e1 + 1.f);
    float s = fmaf(th0, aw.x, th1 * aw.y);
#pragma unroll
    for (int o2 = 32; o2 >= 1; o2 >>= 1) s += __shfl_xor(s, o2, 64);
    float e = ex2(s * L2E);      // no max-subtraction: |s| bounded, e^s safe in f32
    r0 = fmaf(e, h0, r0); r1 = fmaf(e, h1, r1); es += e;
  }
  rsum[w][2 * l] = r0;
  rsum[w][2 * l + 1] = r1;
  if (l == 0) esums[w] = es;
  __syncthreads();
  if (tid < 128) {
    float r = 0.f, et = 0.f;
#pragma unroll
    for (int i = 0; i < 8; i++) { r += rsum[i][tid]; et += esums[i]; }
    float rr = r / et;
    float e2 = ex2(rr * TL2E);
    hstar[tid] = (e2 - 1.f) * rcp_f(e2 + 1.f);
  }
  __syncthreads();
  if (tid < NCLS) {
    float acc = fc_b[tid];
#pragma unroll 4
    for (int hh = 0; hh < 128; hh++) acc = fmaf(hstar[hh], fc_w[hh * NCLS + tid], acc);
    out[b * NCLS + tid] = acc;
    lg[tid] = acc;
  }
  __syncthreads();
  if (tid == 0) {
    int best = 0; float bv = lg[0];
    for (int l2 = 1; l2 < NCLS; l2++)
      if (lg[l2] > bv) { bv = lg[l2]; best = l2; }
    out[2432 + b] = (float)best;   // predict_label_ids
    out[2561 + b] = (float)best;   // probabilities (argmax of softmax == argmax)
  }
}

// ---------------- l2 loss ----------------------------------------------------------
__global__ __launch_bounds__(256) void k_l2(const float* __restrict__ fc_w,
                                            const float* __restrict__ fc_b,
                                            float* __restrict__ out) {
  __shared__ float red[256];
  int tid = threadIdx.x;
  float a = 0.f;
  for (int i = tid; i < 128 * NCLS; i += 256) a += fc_w[i] * fc_w[i];
  if (tid < NCLS) a += fc_b[tid] * fc_b[tid];
  red[tid] = a; __syncthreads();
  for (int s = 128; s >= 1; s >>= 1) {
    if (tid < s) red[tid] += red[tid + s];
    __syncthreads();
  }
  if (tid == 0) out[2560] = 0.5f * red[0];
}

extern "C" void kernel_launch(void* const* d_in, const int* in_sizes, int n_in,
                              void* d_out, int out_size, void* d_ws, size_t ws_size,
                              hipStream_t stream) {
  const int* ids = (const int*)d_in[0];
  const float* table = (const float*)d_in[1];
  const float* fw_k = (const float*)d_in[2];
  const float* fw_b = (const float*)d_in[3];
  const float* bw_k = (const float*)d_in[4];
  const float* bw_b = (const float*)d_in[5];
  const float* att_w = (const float*)d_in[6];
  const float* fc_w = (const float*)d_in[7];
  const float* fc_b = (const float*)d_in[8];
  float* out = (float*)d_out;
  char* ws = (char*)d_ws;

  u16* xs = (u16*)(ws + 0);                    // 16,777,216 B   xs[t*128+b][128] bf16
  u16* wt_bf = (u16*)(ws + 16777216);          //    524,288 B   [2][512][256] bf16
  float* bias_pre = (float*)(ws + 17301504);   //      4,096 B
  u16* hs_fw = (u16*)(ws + 17305600);          // 16,777,216 B   [t][b][u] bf16
  u16* hs_bw = (u16*)(ws + 34082816);          // 16,777,216 B   (end 50,860,032)

  hipLaunchKernelGGL(k_embed, dim3(8192), dim3(256), 0, stream, ids, table, xs);
  hipLaunchKernelGGL(k_prep, dim3(1025), dim3(256), 0, stream, fw_k, bw_k, fw_b, bw_b,
                     wt_bf, bias_pre);
  hipLaunchKernelGGL(k_lstm, dim3(64), dim3(512), 0, stream, wt_bf, bias_pre, xs,
                     hs_fw, hs_bw);
  hipLaunchKernelGGL(k_attn, dim3(128), dim3(512), 0, stream, hs_fw, hs_bw, att_w,
                     fc_w, fc_b, out);
  hipLaunchKernelGGL(k_l2, dim3(1), dim3(256), 0, stream, fc_w, fc_b, out);
}